// Round 5
// baseline (347.613 us; speedup 1.0000x reference)
//
#include <hip/hip_runtime.h>

#define R_TOTAL 12544
#define NTOK    784
#define CDIM    384
#define INNER   1152
#define NHEAD   8
#define HDIM    48
#define BATCH   16
#define SCALE   0.14433756729740643f   // 48^-0.5

typedef unsigned short u16;
typedef unsigned int   u32;
typedef __attribute__((ext_vector_type(8))) short short8;   // 8 bf16, 4 VGPRs
typedef __attribute__((ext_vector_type(4))) float floatx4;  // MFMA C/D

union V8 { uint4 u; short8 s; u16 h[8]; };

// workspace layout (BYTE offsets) — total 38.56 MB, byte-identical to round-2/3/4-proven layout.
// Round 1 proved larger layouts corrupt the harness's pristine input copies.
#define OB_OFF     28901376ull   // Yb bf16 [12544,1152] at 0; Ob bf16 [12544,384] here
#define ST_OFF     38535168ull   // fp32 stats: S1[2304] AB1[2304] S2[768] AB2[768]

__device__ __forceinline__ float b2f(u16 u) {
    union { float f; u32 i; } v; v.i = ((u32)u) << 16; return v.f;
}
__device__ __forceinline__ u16 f2b(float f) {
    union { float f; u32 i; } v; v.f = f;
    u32 r = v.i + 0x7FFFu + ((v.i >> 16) & 1u);   // RNE
    return (u16)(r >> 16);
}
__device__ __forceinline__ u32 pk2(float lo, float hi) {
    return (u32)f2b(lo) | ((u32)f2b(hi) << 16);
}
__device__ __forceinline__ float hswish_f(float v) {
    return v * fminf(fmaxf(v + 3.f, 0.f), 6.f) * (1.f / 6.f);
}

__global__ __launch_bounds__(256) void zero_k(float* __restrict__ p, int n) {
    int i = blockIdx.x * 256 + threadIdx.x;
    if (i < n) p[i] = 0.f;
}

// ---------------------------------------------------------------- MFMA GEMM
// A row-major [M,K] (fp32 or bf16, optional hardswish), Bt row-major [N,K] fp32,
// C = A*Bt^T, out bf16 or fp32. 128x128 tile, BK=32, 4 waves of 64x64.
template<int ABF16, int HSW, int OBF16>
__global__ __launch_bounds__(256) void gemm_mfma_k(
    const void* __restrict__ Ap, const float* __restrict__ Bfp,
    void* __restrict__ Cp, int M, int Nout, int K)
{
    __shared__ u16 As[128 * 40];   // row stride 40 shorts (pad 8) -> 2-way banks
    __shared__ u16 Bs[128 * 40];
    const int t = threadIdx.x;
    const int lane = t & 63, wv = t >> 6;
    const int l15 = lane & 15, quad = lane >> 4;
    const int wm = (wv & 1) * 64, wn = (wv >> 1) * 64;
    const int m0 = blockIdx.y * 128, n0 = blockIdx.x * 128;
    const floatx4 zf = {0.f, 0.f, 0.f, 0.f};

    floatx4 acc[4][4];
    #pragma unroll
    for (int i = 0; i < 4; i++)
        #pragma unroll
        for (int j = 0; j < 4; j++) acc[i][j] = zf;

    for (int k0 = 0; k0 < K; k0 += 32) {
        __syncthreads();
        #pragma unroll
        for (int it = 0; it < 2; it++) {
            const int flat = t + it * 256;           // 0..511
            const int rr = flat >> 2, ss = (flat & 3) * 8;
            uint4 aw;
            if (ABF16) {
                uint4 u = *(const uint4*)((const u16*)Ap + (size_t)(m0 + rr) * K + k0 + ss);
                if (HSW) {
                    aw.x = pk2(hswish_f(b2f((u16)(u.x & 0xffff))), hswish_f(b2f((u16)(u.x >> 16))));
                    aw.y = pk2(hswish_f(b2f((u16)(u.y & 0xffff))), hswish_f(b2f((u16)(u.y >> 16))));
                    aw.z = pk2(hswish_f(b2f((u16)(u.z & 0xffff))), hswish_f(b2f((u16)(u.z >> 16))));
                    aw.w = pk2(hswish_f(b2f((u16)(u.w & 0xffff))), hswish_f(b2f((u16)(u.w >> 16))));
                } else {
                    aw = u;
                }
            } else {
                const float* p = (const float*)Ap + (size_t)(m0 + rr) * K + k0 + ss;
                float4 f0 = *(const float4*)p, f1 = *(const float4*)(p + 4);
                aw.x = pk2(f0.x, f0.y); aw.y = pk2(f0.z, f0.w);
                aw.z = pk2(f1.x, f1.y); aw.w = pk2(f1.z, f1.w);
            }
            *(uint4*)&As[rr * 40 + ss] = aw;
            const float* q = Bfp + (size_t)(n0 + rr) * K + k0 + ss;
            float4 g0 = *(const float4*)q, g1 = *(const float4*)(q + 4);
            uint4 bw;
            bw.x = pk2(g0.x, g0.y); bw.y = pk2(g0.z, g0.w);
            bw.z = pk2(g1.x, g1.y); bw.w = pk2(g1.z, g1.w);
            *(uint4*)&Bs[rr * 40 + ss] = bw;
        }
        __syncthreads();
        short8 af[4], bfr[4];
        #pragma unroll
        for (int mi = 0; mi < 4; mi++)
            af[mi] = *(const short8*)&As[(wm + mi * 16 + l15) * 40 + quad * 8];
        #pragma unroll
        for (int ni = 0; ni < 4; ni++)
            bfr[ni] = *(const short8*)&Bs[(wn + ni * 16 + l15) * 40 + quad * 8];
        #pragma unroll
        for (int mi = 0; mi < 4; mi++)
            #pragma unroll
            for (int ni = 0; ni < 4; ni++)
                acc[mi][ni] = __builtin_amdgcn_mfma_f32_16x16x32_bf16(af[mi], bfr[ni], acc[mi][ni], 0, 0, 0);
    }
    #pragma unroll
    for (int mi = 0; mi < 4; mi++) {
        const int mbase = m0 + wm + mi * 16 + quad * 4;
        #pragma unroll
        for (int ni = 0; ni < 4; ni++) {
            const int n = n0 + wn + ni * 16 + l15;
            #pragma unroll
            for (int reg = 0; reg < 4; reg++) {
                size_t off = (size_t)(mbase + reg) * Nout + n;
                float v = acc[mi][ni][reg];
                if (OBF16) ((u16*)Cp)[off] = f2b(v);
                else       ((float*)Cp)[off] = v;
            }
        }
    }
}

// ---------------------------------------------------------------- column stats (sum, sumsq)
template<int BF16>
__global__ __launch_bounds__(128) void col_stats_k(
    const void* __restrict__ Zp, float* __restrict__ sums, int Ncols)
{
    const int col = blockIdx.x * 128 + threadIdx.x;
    const int r0  = blockIdx.y * 256;
    float s = 0.f, s2 = 0.f;
    if (BF16) {
        const u16* Z = (const u16*)Zp;
        for (int r = r0; r < r0 + 256; r++) {
            float v = b2f(Z[(size_t)r * Ncols + col]);
            s += v; s2 += v * v;
        }
    } else {
        const float* Z = (const float*)Zp;
        for (int r = r0; r < r0 + 256; r++) {
            float v = Z[(size_t)r * Ncols + col];
            s += v; s2 += v * v;
        }
    }
    atomicAdd(&sums[col], s);
    atomicAdd(&sums[Ncols + col], s2);
}

__global__ __launch_bounds__(256) void finalize_bn_k(
    const float* __restrict__ sums, const float* __restrict__ g,
    const float* __restrict__ bvec, float* __restrict__ ab, int Ncols, float invM)
{
    int c = blockIdx.x * 256 + threadIdx.x;
    if (c >= Ncols) return;
    float mean = sums[c] * invM;
    float var  = sums[Ncols + c] * invM - mean * mean;
    float a    = g[c] * rsqrtf(var + 1e-5f);
    ab[c] = a;
    ab[Ncols + c] = bvec[c] - mean * a;
}

// fp32 in-place BN apply (for final output)
__global__ __launch_bounds__(256) void bn_apply_k(
    float* __restrict__ Z, const float* __restrict__ ab, int Ncols, int total4)
{
    for (int i4 = blockIdx.x * 256 + threadIdx.x; i4 < total4; i4 += gridDim.x * 256) {
        int col = (i4 * 4) % Ncols;
        float4 z  = *(float4*)(Z + (size_t)i4 * 4);
        float4 a4 = *(const float4*)(ab + col);
        float4 b4 = *(const float4*)(ab + Ncols + col);
        z.x = a4.x * z.x + b4.x; z.y = a4.y * z.y + b4.y;
        z.z = a4.z * z.z + b4.z; z.w = a4.w * z.w + b4.w;
        *(float4*)(Z + (size_t)i4 * 4) = z;
    }
}

// bf16 in-place BN apply (pre-applies BN1 to Yb so attention stages plain copies)
__global__ __launch_bounds__(256) void bn_apply_bf16_k(
    u16* __restrict__ Z, const float* __restrict__ ab, int Ncols, int total8)
{
    int i8 = blockIdx.x * 256 + threadIdx.x;
    if (i8 >= total8) return;
    int col = (i8 * 8) % Ncols;
    uint4 u = *(uint4*)(Z + (size_t)i8 * 8);
    float4 A0 = *(const float4*)(ab + col),        A1 = *(const float4*)(ab + col + 4);
    float4 B0 = *(const float4*)(ab + Ncols + col), B1 = *(const float4*)(ab + Ncols + col + 4);
    uint4 o;
    o.x = pk2(fmaf(b2f((u16)(u.x & 0xffff)), A0.x, B0.x), fmaf(b2f((u16)(u.x >> 16)), A0.y, B0.y));
    o.y = pk2(fmaf(b2f((u16)(u.y & 0xffff)), A0.z, B0.z), fmaf(b2f((u16)(u.y >> 16)), A0.w, B0.w));
    o.z = pk2(fmaf(b2f((u16)(u.z & 0xffff)), A1.x, B1.x), fmaf(b2f((u16)(u.z >> 16)), A1.y, B1.y));
    o.w = pk2(fmaf(b2f((u16)(u.w & 0xffff)), A1.z, B1.z), fmaf(b2f((u16)(u.w >> 16)), A1.w, B1.w));
    *(uint4*)(Z + (size_t)i8 * 8) = o;
}

// ---------------------------------------------------------------- MFMA flash attention
// grid (bh=128, qt=13): same-(b,h) q-tiles share an XCD -> K/V L2-resident.
// Frag-order LDS (slot = region*64 + lane, 8 shorts/slot) -> all b128 reads conflict-free.
// Softmax without max-subtraction: scores are BN-bounded (|s| <~ 8), exp can't overflow;
// removes all in-loop cross-lane chains (one shfl reduction after the loop).
__global__ __launch_bounds__(256) void attn_mfma_k(
    const u16* __restrict__ Y,
    const float* __restrict__ biases, const int* __restrict__ idxs,
    u16* __restrict__ O)
{
    __shared__ u16 kt[8 * 64 * 8];      // regions (sub*2+c): K[key=sub*16+l15][hd=c*32+quad*8+j]
    __shared__ u16 vt[6 * 64 * 8];      // regions (ns*2+kc): V^T[hd=ns*16+l15][key=kc*32+quad*8+j]
    __shared__ u16 psm[4][2 * 64 * 8];  // per wave, regions kc: P[q=l15][key=kc*32+quad*8+j]
    __shared__ float hb[NTOK];

    const int t = threadIdx.x;
    const int lane = t & 63, wv = t >> 6;
    const int l15 = lane & 15, quad = lane >> 4;
    const int bh = blockIdx.x;
    const int b = bh >> 3, h = bh & 7;
    const int qt = blockIdx.y;
    const int n0 = qt * 64;
    const int bN = b * NTOK;
    const int colQ = h * HDIM, colK = CDIM + colQ, colV = 2 * CDIM + colQ;
    const floatx4 zf = {0.f, 0.f, 0.f, 0.f};

    if (t < 196) *(float4*)&hb[t << 2] = *(const float4*)(biases + (size_t)h * NTOK + (t << 2));
    if (t < 128) {   // zero hd-pad of kt: regions (sub*2+1), lanes 32..63 — never rewritten
        int slot = ((t >> 5) * 2 + 1) * 64 + 32 + (t & 31);
        *(uint4*)&kt[slot * 8] = make_uint4(0u, 0u, 0u, 0u);
    }

    // Q frags (A-layout: m=l15, k=quad*8+j); chunk1 zero past hd=48
    short8 qf0, qf1;
    {
        V8 a0, a1;
        a0.u = make_uint4(0u, 0u, 0u, 0u); a1.u = a0.u;
        int q = n0 + wv * 16 + l15;
        if (q < NTOK) {
            const u16* src = Y + (size_t)(bN + q) * INNER + colQ;
            a0.u = *(const uint4*)(src + quad * 8);
            if (quad < 2) a1.u = *(const uint4*)(src + 32 + quad * 8);
        }
        qf0 = a0.s; qf1 = a1.s;
    }

    // staging items: 64 keys x 6 hd-segs; item f -> key r=f/6, seg s=f%6 (hd=s*8)
    const int r0 = t / 6,        s0 = t % 6;
    const int r1 = (256 + t) / 6, s1 = (256 + t) % 6;
    const bool own1 = (t < 128);
    // K slot: region (r>>4)*2 + (s>>2), lane (s&3)*16 + (r&15)
    const int kslot0 = (((r0 >> 4) * 2 + (s0 >> 2)) * 64 + (s0 & 3) * 16 + (r0 & 15)) * 8;
    const int kslot1 = (((r1 >> 4) * 2 + (s1 >> 2)) * 64 + (s1 & 3) * 16 + (r1 & 15)) * 8;
    // V scatter: region (s>>1)*2 + (r>>5), lane ((r&31)>>3)*16 + (s&1)*8 + j, elem r&7
    const int vbase0 = (((s0 >> 1) * 2 + (r0 >> 5)) * 64 + ((r0 & 31) >> 3) * 16 + (s0 & 1) * 8) * 8 + (r0 & 7);
    const int vbase1 = (((s1 >> 1) * 2 + (r1 >> 5)) * 64 + ((r1 & 31) >> 3) * 16 + (s1 & 1) * 8) * 8 + (r1 & 7);

    V8 pk0, pv0, pk1, pv1;
    {   // prefetch tile 0 (all keys valid)
        pk0.u = *(const uint4*)(Y + (size_t)(bN + r0) * INNER + colK + s0 * 8);
        pv0.u = *(const uint4*)(Y + (size_t)(bN + r0) * INNER + colV + s0 * 8);
        if (own1) {
            pk1.u = *(const uint4*)(Y + (size_t)(bN + r1) * INNER + colK + s1 * 8);
            pv1.u = *(const uint4*)(Y + (size_t)(bN + r1) * INNER + colV + s1 * 8);
        }
    }

    float lsum[4] = {0.f, 0.f, 0.f, 0.f};
    floatx4 oacc[3];
    #pragma unroll
    for (int i = 0; i < 3; i++) oacc[i] = zf;

    for (int mt = 0; mt < 13; mt++) {
        const int m0k = mt * 64;
        __syncthreads();   // all waves done reading kt/vt of prev iter; fences hb/pad at mt=0
        *(uint4*)&kt[kslot0] = pk0.u;
        #pragma unroll
        for (int j = 0; j < 8; j++) vt[vbase0 + j * 8] = pv0.h[j];
        if (own1) {
            *(uint4*)&kt[kslot1] = pk1.u;
            #pragma unroll
            for (int j = 0; j < 8; j++) vt[vbase1 + j * 8] = pv1.h[j];
        }
        __syncthreads();

        // prefetch next tile (overlaps compute below)
        if (mt + 1 < 13) {
            const int mn = (mt + 1) * 64;
            uint4 z = make_uint4(0u, 0u, 0u, 0u);
            const int key0 = mn + r0;
            pk0.u = z; pv0.u = z;
            if (key0 < NTOK) {
                pk0.u = *(const uint4*)(Y + (size_t)(bN + key0) * INNER + colK + s0 * 8);
                pv0.u = *(const uint4*)(Y + (size_t)(bN + key0) * INNER + colV + s0 * 8);
            }
            if (own1) {
                const int key1 = mn + r1;
                pk1.u = z; pv1.u = z;
                if (key1 < NTOK) {
                    pk1.u = *(const uint4*)(Y + (size_t)(bN + key1) * INNER + colK + s1 * 8);
                    pv1.u = *(const uint4*)(Y + (size_t)(bN + key1) * INNER + colV + s1 * 8);
                }
            }
        }

        // ---- QK^T: D[q=quad*4+reg][key=sub*16+l15]; conflict-free b128 reads
        floatx4 sf[4];
        #pragma unroll
        for (int sub = 0; sub < 4; sub++) {
            short8 kb0 = *(const short8*)&kt[((sub * 2 + 0) * 64 + lane) * 8];
            short8 kb1 = *(const short8*)&kt[((sub * 2 + 1) * 64 + lane) * 8];
            floatx4 c = zf;
            c = __builtin_amdgcn_mfma_f32_16x16x32_bf16(qf0, kb0, c, 0, 0, 0);
            c = __builtin_amdgcn_mfma_f32_16x16x32_bf16(qf1, kb1, c, 0, 0, 0);
            sf[sub] = c;
        }

        // ---- p = exp(s*scale + bias); no max-sub, no in-loop reductions
        #pragma unroll
        for (int reg = 0; reg < 4; reg++) {
            int q = n0 + wv * 16 + quad * 4 + reg;
            int qc = q < NTOK ? q : NTOK - 1;
            const int* idxrow = idxs + (size_t)qc * NTOK;
            #pragma unroll
            for (int sub = 0; sub < 4; sub++) {
                int key = m0k + sub * 16 + l15;
                float p = 0.f;
                if (key < NTOK)
                    p = __expf(fmaf(sf[sub][reg], SCALE, hb[idxrow[key]]));
                lsum[reg] += p;
                int slot = (sub >> 1) * 64 + ((sub & 1) * 2 + (l15 >> 3)) * 16 + quad * 4 + reg;
                psm[wv][slot * 8 + (l15 & 7)] = f2b(p);
            }
        }

        // ---- PV: A=P (own-wave psm, in-order DS), B=V^T; conflict-free b128 reads
        #pragma unroll
        for (int kc = 0; kc < 2; kc++) {
            short8 pa = *(const short8*)&psm[wv][(kc * 64 + lane) * 8];
            #pragma unroll
            for (int ns = 0; ns < 3; ns++) {
                short8 vb = *(const short8*)&vt[((ns * 2 + kc) * 64 + lane) * 8];
                oacc[ns] = __builtin_amdgcn_mfma_f32_16x16x32_bf16(pa, vb, oacc[ns], 0, 0, 0);
            }
        }
    }

    // ---- single post-loop reduction of lsum across the 16 key-lanes
    #pragma unroll
    for (int reg = 0; reg < 4; reg++) {
        float s = lsum[reg];
        s += __shfl_xor(s, 1);
        s += __shfl_xor(s, 2);
        s += __shfl_xor(s, 4);
        s += __shfl_xor(s, 8);
        lsum[reg] = s;
    }

    // ---- epilogue: O[q][h*48 + ns*16 + l15] = hardswish(oacc/lsum)  (gemm2 HSW=0)
    #pragma unroll
    for (int reg = 0; reg < 4; reg++) {
        int q = n0 + wv * 16 + quad * 4 + reg;
        if (q < NTOK) {
            float rl = 1.f / lsum[reg];
            u16* dst = O + (size_t)(bN + q) * CDIM + colQ;
            dst[l15]      = f2b(hswish_f(oacc[0][reg] * rl));
            dst[16 + l15] = f2b(hswish_f(oacc[1][reg] * rl));
            dst[32 + l15] = f2b(hswish_f(oacc[2][reg] * rl));
        }
    }
}

// ---------------------------------------------------------------- launch
extern "C" void kernel_launch(void* const* d_in, const int* in_sizes, int n_in,
                              void* d_out, int out_size, void* d_ws, size_t ws_size,
                              hipStream_t stream)
{
    const float* x     = (const float*)d_in[0];
    const float* Wqkv  = (const float*)d_in[1];
    const float* g1    = (const float*)d_in[2];
    const float* b1    = (const float*)d_in[3];
    const float* Wproj = (const float*)d_in[4];
    const float* g2    = (const float*)d_in[5];
    const float* b2    = (const float*)d_in[6];
    const float* bias  = (const float*)d_in[7];
    const int*   idxs  = (const int*)d_in[8];
    float* out = (float*)d_out;
    char*  wsb = (char*)d_ws;

    u16*   Yb  = (u16*)wsb;                    // 28.9 MB
    u16*   Ob  = (u16*)(wsb + OB_OFF);         // 9.6 MB
    float* S1  = (float*)(wsb + ST_OFF);       // 2304
    float* AB1 = S1 + 2304;                    // 2304
    float* S2  = AB1 + 2304;                   // 768
    float* AB2 = S2 + 768;                     // 768

    zero_k<<<24, 256, 0, stream>>>(S1, 6144);

    // GEMM1 (MFMA): Ybf16 = x @ Wqkv^T   [12544,1152]
    gemm_mfma_k<0, 0, 1><<<dim3(INNER / 128, R_TOTAL / 128), 256, 0, stream>>>(
        x, Wqkv, Yb, R_TOTAL, INNER, CDIM);

    // BN1 stats -> a, bb; then pre-apply BN to Yb in place
    col_stats_k<1><<<dim3(INNER / 128, R_TOTAL / 256), 128, 0, stream>>>(Yb, S1, INNER);
    finalize_bn_k<<<(INNER + 255) / 256, 256, 0, stream>>>(S1, g1, b1, AB1, INNER, 1.f / R_TOTAL);
    bn_apply_bf16_k<<<(R_TOTAL * INNER / 8 + 255) / 256, 256, 0, stream>>>(
        Yb, AB1, INNER, R_TOTAL * INNER / 8);

    // attention (MFMA, frag-order LDS, no-max softmax, reg-prefetch, fused hardswish)
    attn_mfma_k<<<dim3(NHEAD * BATCH, 13), 256, 0, stream>>>(Yb, bias, idxs, Ob);

    // GEMM2 (MFMA): out = O_hsw @ Wproj^T   [12544,384]
    gemm_mfma_k<1, 0, 0><<<dim3(CDIM / 128, R_TOTAL / 128), 256, 0, stream>>>(
        Ob, Wproj, out, R_TOTAL, CDIM, CDIM);

    // BN2 stats -> normalize out in place
    col_stats_k<0><<<dim3(CDIM / 128, R_TOTAL / 256), 128, 0, stream>>>(out, S2, CDIM);
    finalize_bn_k<<<(CDIM + 255) / 256, 256, 0, stream>>>(S2, g2, b2, AB2, CDIM, 1.f / R_TOTAL);
    bn_apply_k<<<1024, 256, 0, stream>>>(out, AB2, CDIM, (R_TOTAL * CDIM) / 4);
}

// Round 6
// 322.223 us; speedup vs baseline: 1.0788x; 1.0788x over previous
//
#include <hip/hip_runtime.h>

#define R_TOTAL 12544
#define NTOK    784
#define CDIM    384
#define INNER   1152
#define NHEAD   8
#define HDIM    48
#define BATCH   16
#define SCALE   0.14433756729740643f   // 48^-0.5

typedef unsigned short u16;
typedef unsigned int   u32;
typedef __attribute__((ext_vector_type(8))) short short8;   // 8 bf16, 4 VGPRs
typedef __attribute__((ext_vector_type(4))) float floatx4;  // MFMA C/D

union V8 { uint4 u; short8 s; u16 h[8]; };

// workspace layout (BYTE offsets) — total 38.56 MB, byte-identical to rounds 2-5 (proven safe).
#define OB_OFF     28901376ull   // Yb bf16 [12544,1152] at 0; Ob bf16 [12544,384] here
#define ST_OFF     38535168ull   // fp32 stats: S1[2304] AB1[2304] S2[768] AB2[768]

__device__ __forceinline__ float b2f(u16 u) {
    union { float f; u32 i; } v; v.i = ((u32)u) << 16; return v.f;
}
__device__ __forceinline__ u16 f2b(float f) {
    union { float f; u32 i; } v; v.f = f;
    u32 r = v.i + 0x7FFFu + ((v.i >> 16) & 1u);   // RNE
    return (u16)(r >> 16);
}
__device__ __forceinline__ u32 pk2(float lo, float hi) {
    return (u32)f2b(lo) | ((u32)f2b(hi) << 16);
}
__device__ __forceinline__ float hswish_f(float v) {
    return v * fminf(fmaxf(v + 3.f, 0.f), 6.f) * (1.f / 6.f);
}

__global__ __launch_bounds__(256) void zero_k(float* __restrict__ p, int n) {
    int i = blockIdx.x * 256 + threadIdx.x;
    if (i < n) p[i] = 0.f;
}

// ---------------------------------------------------------------- MFMA GEMM
template<int ABF16, int HSW, int OBF16>
__global__ __launch_bounds__(256) void gemm_mfma_k(
    const void* __restrict__ Ap, const float* __restrict__ Bfp,
    void* __restrict__ Cp, int M, int Nout, int K)
{
    __shared__ u16 As[128 * 40];
    __shared__ u16 Bs[128 * 40];
    const int t = threadIdx.x;
    const int lane = t & 63, wv = t >> 6;
    const int l15 = lane & 15, quad = lane >> 4;
    const int wm = (wv & 1) * 64, wn = (wv >> 1) * 64;
    const int m0 = blockIdx.y * 128, n0 = blockIdx.x * 128;
    const floatx4 zf = {0.f, 0.f, 0.f, 0.f};

    floatx4 acc[4][4];
    #pragma unroll
    for (int i = 0; i < 4; i++)
        #pragma unroll
        for (int j = 0; j < 4; j++) acc[i][j] = zf;

    for (int k0 = 0; k0 < K; k0 += 32) {
        __syncthreads();
        #pragma unroll
        for (int it = 0; it < 2; it++) {
            const int flat = t + it * 256;
            const int rr = flat >> 2, ss = (flat & 3) * 8;
            uint4 aw;
            if (ABF16) {
                uint4 u = *(const uint4*)((const u16*)Ap + (size_t)(m0 + rr) * K + k0 + ss);
                if (HSW) {
                    aw.x = pk2(hswish_f(b2f((u16)(u.x & 0xffff))), hswish_f(b2f((u16)(u.x >> 16))));
                    aw.y = pk2(hswish_f(b2f((u16)(u.y & 0xffff))), hswish_f(b2f((u16)(u.y >> 16))));
                    aw.z = pk2(hswish_f(b2f((u16)(u.z & 0xffff))), hswish_f(b2f((u16)(u.z >> 16))));
                    aw.w = pk2(hswish_f(b2f((u16)(u.w & 0xffff))), hswish_f(b2f((u16)(u.w >> 16))));
                } else {
                    aw = u;
                }
            } else {
                const float* p = (const float*)Ap + (size_t)(m0 + rr) * K + k0 + ss;
                float4 f0 = *(const float4*)p, f1 = *(const float4*)(p + 4);
                aw.x = pk2(f0.x, f0.y); aw.y = pk2(f0.z, f0.w);
                aw.z = pk2(f1.x, f1.y); aw.w = pk2(f1.z, f1.w);
            }
            *(uint4*)&As[rr * 40 + ss] = aw;
            const float* q = Bfp + (size_t)(n0 + rr) * K + k0 + ss;
            float4 g0 = *(const float4*)q, g1 = *(const float4*)(q + 4);
            uint4 bw;
            bw.x = pk2(g0.x, g0.y); bw.y = pk2(g0.z, g0.w);
            bw.z = pk2(g1.x, g1.y); bw.w = pk2(g1.z, g1.w);
            *(uint4*)&Bs[rr * 40 + ss] = bw;
        }
        __syncthreads();
        short8 af[4], bfr[4];
        #pragma unroll
        for (int mi = 0; mi < 4; mi++)
            af[mi] = *(const short8*)&As[(wm + mi * 16 + l15) * 40 + quad * 8];
        #pragma unroll
        for (int ni = 0; ni < 4; ni++)
            bfr[ni] = *(const short8*)&Bs[(wn + ni * 16 + l15) * 40 + quad * 8];
        #pragma unroll
        for (int mi = 0; mi < 4; mi++)
            #pragma unroll
            for (int ni = 0; ni < 4; ni++)
                acc[mi][ni] = __builtin_amdgcn_mfma_f32_16x16x32_bf16(af[mi], bfr[ni], acc[mi][ni], 0, 0, 0);
    }
    #pragma unroll
    for (int mi = 0; mi < 4; mi++) {
        const int mbase = m0 + wm + mi * 16 + quad * 4;
        #pragma unroll
        for (int ni = 0; ni < 4; ni++) {
            const int n = n0 + wn + ni * 16 + l15;
            #pragma unroll
            for (int reg = 0; reg < 4; reg++) {
                size_t off = (size_t)(mbase + reg) * Nout + n;
                float v = acc[mi][ni][reg];
                if (OBF16) ((u16*)Cp)[off] = f2b(v);
                else       ((float*)Cp)[off] = v;
            }
        }
    }
}

// ---------------------------------------------------------------- column stats
template<int BF16>
__global__ __launch_bounds__(128) void col_stats_k(
    const void* __restrict__ Zp, float* __restrict__ sums, int Ncols)
{
    const int col = blockIdx.x * 128 + threadIdx.x;
    const int r0  = blockIdx.y * 256;
    float s = 0.f, s2 = 0.f;
    if (BF16) {
        const u16* Z = (const u16*)Zp;
        for (int r = r0; r < r0 + 256; r++) {
            float v = b2f(Z[(size_t)r * Ncols + col]);
            s += v; s2 += v * v;
        }
    } else {
        const float* Z = (const float*)Zp;
        for (int r = r0; r < r0 + 256; r++) {
            float v = Z[(size_t)r * Ncols + col];
            s += v; s2 += v * v;
        }
    }
    atomicAdd(&sums[col], s);
    atomicAdd(&sums[Ncols + col], s2);
}

__global__ __launch_bounds__(256) void finalize_bn_k(
    const float* __restrict__ sums, const float* __restrict__ g,
    const float* __restrict__ bvec, float* __restrict__ ab, int Ncols, float invM)
{
    int c = blockIdx.x * 256 + threadIdx.x;
    if (c >= Ncols) return;
    float mean = sums[c] * invM;
    float var  = sums[Ncols + c] * invM - mean * mean;
    float a    = g[c] * rsqrtf(var + 1e-5f);
    ab[c] = a;
    ab[Ncols + c] = bvec[c] - mean * a;
}

__global__ __launch_bounds__(256) void bn_apply_k(
    float* __restrict__ Z, const float* __restrict__ ab, int Ncols, int total4)
{
    for (int i4 = blockIdx.x * 256 + threadIdx.x; i4 < total4; i4 += gridDim.x * 256) {
        int col = (i4 * 4) % Ncols;
        float4 z  = *(float4*)(Z + (size_t)i4 * 4);
        float4 a4 = *(const float4*)(ab + col);
        float4 b4 = *(const float4*)(ab + Ncols + col);
        z.x = a4.x * z.x + b4.x; z.y = a4.y * z.y + b4.y;
        z.z = a4.z * z.z + b4.z; z.w = a4.w * z.w + b4.w;
        *(float4*)(Z + (size_t)i4 * 4) = z;
    }
}

__global__ __launch_bounds__(256) void bn_apply_bf16_k(
    u16* __restrict__ Z, const float* __restrict__ ab, int Ncols, int total8)
{
    int i8 = blockIdx.x * 256 + threadIdx.x;
    if (i8 >= total8) return;
    int col = (i8 * 8) % Ncols;
    uint4 u = *(uint4*)(Z + (size_t)i8 * 8);
    float4 A0 = *(const float4*)(ab + col),         A1 = *(const float4*)(ab + col + 4);
    float4 B0 = *(const float4*)(ab + Ncols + col), B1 = *(const float4*)(ab + Ncols + col + 4);
    uint4 o;
    o.x = pk2(fmaf(b2f((u16)(u.x & 0xffff)), A0.x, B0.x), fmaf(b2f((u16)(u.x >> 16)), A0.y, B0.y));
    o.y = pk2(fmaf(b2f((u16)(u.y & 0xffff)), A0.z, B0.z), fmaf(b2f((u16)(u.y >> 16)), A0.w, B0.w));
    o.z = pk2(fmaf(b2f((u16)(u.z & 0xffff)), A1.x, B1.x), fmaf(b2f((u16)(u.z >> 16)), A1.y, B1.y));
    o.w = pk2(fmaf(b2f((u16)(u.w & 0xffff)), A1.z, B1.z), fmaf(b2f((u16)(u.w >> 16)), A1.w, B1.w));
    *(uint4*)(Z + (size_t)i8 * 8) = o;
}

// ---------------------------------------------------------------- MFMA flash attention v3
// Operand-swapped: S^T = K*Q^T (K A-frags straight from global/L2, no kt LDS);
// P^T written with 4 ds_write_b64; PV^T: O^T = V^T*P^T (A=V^T frag-order LDS, B=P^T b128).
// vt double-buffered -> 1 barrier/iter. lsum is a per-lane scalar (2 shuffles post-loop).
__global__ __launch_bounds__(256) void attn_mfma_k(
    const u16* __restrict__ Y,
    const float* __restrict__ biases, const int* __restrict__ idxs,
    u16* __restrict__ O)
{
    __shared__ u16 vt[2][6 * 64 * 8];   // double-buffered V^T, frag-order
    __shared__ u16 psm[4][2 * 64 * 8];  // per-wave P^T, frag-order
    __shared__ float hb[NTOK];

    const int t = threadIdx.x;
    const int lane = t & 63, wv = t >> 6;
    const int l15 = lane & 15, quad = lane >> 4;
    const int bh = blockIdx.x;
    const int b = bh >> 3, h = bh & 7;
    const int qt = blockIdx.y;
    const int n0 = qt * 64;
    const int bN = b * NTOK;
    const int colQ = h * HDIM, colK = CDIM + colQ, colV = 2 * CDIM + colQ;
    const floatx4 zf = {0.f, 0.f, 0.f, 0.f};

    if (t < 196) *(float4*)&hb[t << 2] = *(const float4*)(biases + (size_t)h * NTOK + (t << 2));

    // this lane's q row (lane l15 = q in the swapped layout)
    const int q  = n0 + wv * 16 + l15;
    const int qr = q < NTOK ? q : NTOK - 1;

    // Q B-frags: B[k=d=quad*8+j][n=q=l15]; chunk1 zeroed for quad>=2 (d pad 48..63)
    short8 qf0, qf1;
    {
        V8 a0, a1;
        a1.u = make_uint4(0u, 0u, 0u, 0u);
        const u16* src = Y + (size_t)(bN + qr) * INNER + colQ;
        a0.u = *(const uint4*)(src + quad * 8);
        if (quad < 2) a1.u = *(const uint4*)(src + 32 + quad * 8);
        qf0 = a0.s; qf1 = a1.s;
    }

    // V staging items: item f -> key r=f/6, seg s=f%6 (8 d's); frag-order scatter dests
    const int r0 = t / 6,         s0 = t % 6;
    const int r1 = (256 + t) / 6, s1 = (256 + t) % 6;
    const bool own1 = (t < 128);
    const int vbase0 = (((s0 >> 1) * 2 + (r0 >> 5)) * 64 + ((r0 & 31) >> 3) * 16 + (s0 & 1) * 8) * 8 + (r0 & 7);
    const int vbase1 = (((s1 >> 1) * 2 + (r1 >> 5)) * 64 + ((r1 & 31) >> 3) * 16 + (s1 & 1) * 8) * 8 + (r1 & 7);

    // preload V tile 0 and write vt[0] (fenced by first in-loop barrier)
    V8 pv0, pv1;
    pv0.u = *(const uint4*)(Y + (size_t)(bN + r0) * INNER + colV + s0 * 8);
    if (own1) pv1.u = *(const uint4*)(Y + (size_t)(bN + r1) * INNER + colV + s1 * 8);
    {
        u16* vtb = vt[0];
        #pragma unroll
        for (int j = 0; j < 8; j++) vtb[vbase0 + j * 8] = pv0.h[j];
        if (own1) {
            #pragma unroll
            for (int j = 0; j < 8; j++) vtb[vbase1 + j * 8] = pv1.h[j];
        }
    }

    float lsum = 0.f;
    floatx4 oacc[3];
    #pragma unroll
    for (int i = 0; i < 3; i++) oacc[i] = zf;

    const int* idxrow = idxs + (size_t)qr * NTOK;
    const int psbase = ((quad >> 1) * 16 + l15) * 8 + (quad & 1) * 4;  // + (sub>>1)*512 + (sub&1)*256

    for (int mt = 0; mt < 13; mt++) {
        const int m0k = mt * 64;
        __syncthreads();   // vt[mt&1] fully staged (prev iter / preloop); psm/hb fenced at mt=0

        // K A-frags for this tile, straight from global (L2-resident; rows clamped, masked via p)
        V8 kfr[4][2];
        #pragma unroll
        for (int sub = 0; sub < 4; sub++) {
            int key = m0k + sub * 16 + l15;
            int kr  = key < NTOK ? key : NTOK - 1;
            const u16* src = Y + (size_t)(bN + kr) * INNER + colK;
            kfr[sub][0].u = *(const uint4*)(src + quad * 8);
            kfr[sub][1].u = *(const uint4*)(src + 32 + quad * 8);   // quad>=2 garbage, B-side zero
        }

        // prefetch V tile mt+1 into regs (written to the other vt buffer below)
        if (mt + 1 < 13) {
            const int mn = (mt + 1) * 64;
            int k0v = mn + r0; k0v = k0v < NTOK ? k0v : NTOK - 1;
            pv0.u = *(const uint4*)(Y + (size_t)(bN + k0v) * INNER + colV + s0 * 8);
            if (own1) {
                int k1v = mn + r1; k1v = k1v < NTOK ? k1v : NTOK - 1;
                pv1.u = *(const uint4*)(Y + (size_t)(bN + k1v) * INNER + colV + s1 * 8);
            }
        }

        // ---- S^T = K*Q^T: D[m=key=quad*4+reg (+sub*16)][n=q=l15]
        floatx4 sf[4];
        #pragma unroll
        for (int sub = 0; sub < 4; sub++) {
            floatx4 c = zf;
            c = __builtin_amdgcn_mfma_f32_16x16x32_bf16(kfr[sub][0].s, qf0, c, 0, 0, 0);
            c = __builtin_amdgcn_mfma_f32_16x16x32_bf16(kfr[sub][1].s, qf1, c, 0, 0, 0);
            sf[sub] = c;
        }

        // ---- bias + exp + P^T -> psm (one b64 write per sub)
        #pragma unroll
        for (int sub = 0; sub < 4; sub++) {
            int kb  = m0k + sub * 16 + quad * 4;
            int kbc = kb <= NTOK - 4 ? kb : NTOK - 4;
            int4 iv = *(const int4*)(idxrow + kbc);
            float pr[4];
            #pragma unroll
            for (int reg = 0; reg < 4; reg++) {
                int key = kb + reg;
                int ivr = (reg == 0) ? iv.x : (reg == 1) ? iv.y : (reg == 2) ? iv.z : iv.w;
                float p = 0.f;
                if (key < NTOK)
                    p = __expf(fmaf(sf[sub][reg], SCALE, hb[ivr]));
                pr[reg] = p;
                lsum += p;
            }
            int addr = psbase + (sub >> 1) * 512 + (sub & 1) * 256;
            *(uint2*)&psm[wv][addr] = make_uint2(pk2(pr[0], pr[1]), pk2(pr[2], pr[3]));
        }

        // ---- write vt for next tile (prefetched regs have landed by now)
        if (mt + 1 < 13) {
            u16* vtb = vt[(mt + 1) & 1];
            #pragma unroll
            for (int j = 0; j < 8; j++) vtb[vbase0 + j * 8] = pv0.h[j];
            if (own1) {
                #pragma unroll
                for (int j = 0; j < 8; j++) vtb[vbase1 + j * 8] = pv1.h[j];
            }
        }

        // ---- O^T += V^T * P^T  (A=V^T, B=P^T; same-wave psm ordering is in-order DS)
        const u16* vtb = vt[mt & 1];
        #pragma unroll
        for (int kc = 0; kc < 2; kc++) {
            short8 pb = *(const short8*)&psm[wv][(kc * 64 + lane) * 8];
            #pragma unroll
            for (int ns = 0; ns < 3; ns++) {
                short8 va = *(const short8*)&vtb[((ns * 2 + kc) * 64 + lane) * 8];
                oacc[ns] = __builtin_amdgcn_mfma_f32_16x16x32_bf16(va, pb, oacc[ns], 0, 0, 0);
            }
        }
    }

    // ---- reduce lsum over the 4 quads (same q = same l15)
    lsum += __shfl_xor(lsum, 16);
    lsum += __shfl_xor(lsum, 32);

    // ---- epilogue: O[q][colQ + ns*16 + quad*4 + reg] = hardswish(O^T/lsum)
    if (q < NTOK) {
        float rl = 1.f / lsum;
        u16* dst = O + (size_t)(bN + q) * CDIM + colQ;
        #pragma unroll
        for (int ns = 0; ns < 3; ns++)
            #pragma unroll
            for (int reg = 0; reg < 4; reg++)
                dst[ns * 16 + quad * 4 + reg] = f2b(hswish_f(oacc[ns][reg] * rl));
    }
}

// ---------------------------------------------------------------- launch
extern "C" void kernel_launch(void* const* d_in, const int* in_sizes, int n_in,
                              void* d_out, int out_size, void* d_ws, size_t ws_size,
                              hipStream_t stream)
{
    const float* x     = (const float*)d_in[0];
    const float* Wqkv  = (const float*)d_in[1];
    const float* g1    = (const float*)d_in[2];
    const float* b1    = (const float*)d_in[3];
    const float* Wproj = (const float*)d_in[4];
    const float* g2    = (const float*)d_in[5];
    const float* b2    = (const float*)d_in[6];
    const float* bias  = (const float*)d_in[7];
    const int*   idxs  = (const int*)d_in[8];
    float* out = (float*)d_out;
    char*  wsb = (char*)d_ws;

    u16*   Yb  = (u16*)wsb;
    u16*   Ob  = (u16*)(wsb + OB_OFF);
    float* S1  = (float*)(wsb + ST_OFF);
    float* AB1 = S1 + 2304;
    float* S2  = AB1 + 2304;
    float* AB2 = S2 + 768;

    zero_k<<<24, 256, 0, stream>>>(S1, 6144);

    gemm_mfma_k<0, 0, 1><<<dim3(INNER / 128, R_TOTAL / 128), 256, 0, stream>>>(
        x, Wqkv, Yb, R_TOTAL, INNER, CDIM);

    col_stats_k<1><<<dim3(INNER / 128, R_TOTAL / 256), 128, 0, stream>>>(Yb, S1, INNER);
    finalize_bn_k<<<(INNER + 255) / 256, 256, 0, stream>>>(S1, g1, b1, AB1, INNER, 1.f / R_TOTAL);
    bn_apply_bf16_k<<<(R_TOTAL * INNER / 8 + 255) / 256, 256, 0, stream>>>(
        Yb, AB1, INNER, R_TOTAL * INNER / 8);

    attn_mfma_k<<<dim3(NHEAD * BATCH, 13), 256, 0, stream>>>(Yb, bias, idxs, Ob);

    gemm_mfma_k<1, 0, 0><<<dim3(CDIM / 128, R_TOTAL / 128), 256, 0, stream>>>(
        Ob, Wproj, out, R_TOTAL, CDIM, CDIM);

    col_stats_k<0><<<dim3(CDIM / 128, R_TOTAL / 256), 128, 0, stream>>>(out, S2, CDIM);
    finalize_bn_k<<<(CDIM + 255) / 256, 256, 0, stream>>>(S2, g2, b2, AB2, CDIM, 1.f / R_TOTAL);
    bn_apply_k<<<1024, 256, 0, stream>>>(out, AB2, CDIM, (R_TOTAL * CDIM) / 4);
}

// Round 7
// 262.421 us; speedup vs baseline: 1.3246x; 1.2279x over previous
//
#include <hip/hip_runtime.h>

#define R_TOTAL 12544
#define NTOK    784
#define CDIM    384
#define INNER   1152
#define NHEAD   8
#define HDIM    48
#define BATCH   16
#define SCALE   0.14433756729740643f   // 48^-0.5

typedef unsigned short u16;
typedef unsigned int   u32;
typedef __attribute__((ext_vector_type(8))) short short8;   // 8 bf16, 4 VGPRs
typedef __attribute__((ext_vector_type(4))) float floatx4;  // MFMA C/D

union V8 { uint4 u; short8 s; u16 h[8]; };

// workspace layout (BYTE offsets) — total 38.56 MB, byte-identical to rounds 2-6 (proven safe).
#define OB_OFF     28901376ull   // Yb bf16 [12544,1152] at 0; Ob bf16 [12544,384] here
#define ST_OFF     38535168ull   // fp32 stats: S1[2304] AB1[2304] S2[768] AB2[768]

__device__ __forceinline__ float b2f(u16 u) {
    union { float f; u32 i; } v; v.i = ((u32)u) << 16; return v.f;
}
__device__ __forceinline__ u16 f2b(float f) {
    union { float f; u32 i; } v; v.f = f;
    u32 r = v.i + 0x7FFFu + ((v.i >> 16) & 1u);   // RNE
    return (u16)(r >> 16);
}
__device__ __forceinline__ u32 pk2(float lo, float hi) {
    return (u32)f2b(lo) | ((u32)f2b(hi) << 16);
}
__device__ __forceinline__ float hswish_f(float v) {
    return v * fminf(fmaxf(v + 3.f, 0.f), 6.f) * (1.f / 6.f);
}

__global__ __launch_bounds__(256) void zero_k(float* __restrict__ p, int n) {
    int i = blockIdx.x * 256 + threadIdx.x;
    if (i < n) p[i] = 0.f;
}

// ---------------------------------------------------------------- MFMA GEMM (+fused BN col stats)
// A row-major [M,K] (fp32 or bf16, opt hardswish), Bt row-major [N,K] fp32, C=A*Bt^T.
// STATS: atomically accumulate per-column sum/sumsq of the STORED values into sums[0..Nout)/[Nout..2Nout).
template<int ABF16, int HSW, int OBF16>
__global__ __launch_bounds__(256) void gemm_mfma_k(
    const void* __restrict__ Ap, const float* __restrict__ Bfp,
    void* __restrict__ Cp, float* __restrict__ sums, int M, int Nout, int K)
{
    __shared__ u16 As[128 * 40];
    __shared__ u16 Bs[128 * 40];
    const int t = threadIdx.x;
    const int lane = t & 63, wv = t >> 6;
    const int l15 = lane & 15, quad = lane >> 4;
    const int wm = (wv & 1) * 64, wn = (wv >> 1) * 64;
    const int m0 = blockIdx.y * 128, n0 = blockIdx.x * 128;
    const floatx4 zf = {0.f, 0.f, 0.f, 0.f};

    floatx4 acc[4][4];
    #pragma unroll
    for (int i = 0; i < 4; i++)
        #pragma unroll
        for (int j = 0; j < 4; j++) acc[i][j] = zf;

    for (int k0 = 0; k0 < K; k0 += 32) {
        __syncthreads();
        #pragma unroll
        for (int it = 0; it < 2; it++) {
            const int flat = t + it * 256;
            const int rr = flat >> 2, ss = (flat & 3) * 8;
            uint4 aw;
            if (ABF16) {
                uint4 u = *(const uint4*)((const u16*)Ap + (size_t)(m0 + rr) * K + k0 + ss);
                if (HSW) {
                    aw.x = pk2(hswish_f(b2f((u16)(u.x & 0xffff))), hswish_f(b2f((u16)(u.x >> 16))));
                    aw.y = pk2(hswish_f(b2f((u16)(u.y & 0xffff))), hswish_f(b2f((u16)(u.y >> 16))));
                    aw.z = pk2(hswish_f(b2f((u16)(u.z & 0xffff))), hswish_f(b2f((u16)(u.z >> 16))));
                    aw.w = pk2(hswish_f(b2f((u16)(u.w & 0xffff))), hswish_f(b2f((u16)(u.w >> 16))));
                } else {
                    aw = u;
                }
            } else {
                const float* p = (const float*)Ap + (size_t)(m0 + rr) * K + k0 + ss;
                float4 f0 = *(const float4*)p, f1 = *(const float4*)(p + 4);
                aw.x = pk2(f0.x, f0.y); aw.y = pk2(f0.z, f0.w);
                aw.z = pk2(f1.x, f1.y); aw.w = pk2(f1.z, f1.w);
            }
            *(uint4*)&As[rr * 40 + ss] = aw;
            const float* q = Bfp + (size_t)(n0 + rr) * K + k0 + ss;
            float4 g0 = *(const float4*)q, g1 = *(const float4*)(q + 4);
            uint4 bw;
            bw.x = pk2(g0.x, g0.y); bw.y = pk2(g0.z, g0.w);
            bw.z = pk2(g1.x, g1.y); bw.w = pk2(g1.z, g1.w);
            *(uint4*)&Bs[rr * 40 + ss] = bw;
        }
        __syncthreads();
        short8 af[4], bfr[4];
        #pragma unroll
        for (int mi = 0; mi < 4; mi++)
            af[mi] = *(const short8*)&As[(wm + mi * 16 + l15) * 40 + quad * 8];
        #pragma unroll
        for (int ni = 0; ni < 4; ni++)
            bfr[ni] = *(const short8*)&Bs[(wn + ni * 16 + l15) * 40 + quad * 8];
        #pragma unroll
        for (int mi = 0; mi < 4; mi++)
            #pragma unroll
            for (int ni = 0; ni < 4; ni++)
                acc[mi][ni] = __builtin_amdgcn_mfma_f32_16x16x32_bf16(af[mi], bfr[ni], acc[mi][ni], 0, 0, 0);
    }

    float cs[4] = {0.f, 0.f, 0.f, 0.f}, cq[4] = {0.f, 0.f, 0.f, 0.f};
    #pragma unroll
    for (int mi = 0; mi < 4; mi++) {
        const int mbase = m0 + wm + mi * 16 + quad * 4;
        #pragma unroll
        for (int ni = 0; ni < 4; ni++) {
            const int n = n0 + wn + ni * 16 + l15;
            #pragma unroll
            for (int reg = 0; reg < 4; reg++) {
                size_t off = (size_t)(mbase + reg) * Nout + n;
                float v = acc[mi][ni][reg];
                float vv;
                if (OBF16) {
                    u16 hv = f2b(v);
                    ((u16*)Cp)[off] = hv;
                    vv = b2f(hv);          // stats over the values attention will read
                } else {
                    ((float*)Cp)[off] = v;
                    vv = v;
                }
                cs[ni] += vv;
                cq[ni] += vv * vv;
            }
        }
    }
    // per-column reduce over the 4 quads, one atomic per col per wave
    #pragma unroll
    for (int ni = 0; ni < 4; ni++) {
        float s = cs[ni], sq = cq[ni];
        s  += __shfl_xor(s, 16);  s  += __shfl_xor(s, 32);
        sq += __shfl_xor(sq, 16); sq += __shfl_xor(sq, 32);
        if (quad == 0) {
            int col = n0 + wn + ni * 16 + l15;
            atomicAdd(&sums[col], s);
            atomicAdd(&sums[Nout + col], sq);
        }
    }
}

__global__ __launch_bounds__(256) void finalize_bn_k(
    const float* __restrict__ sums, const float* __restrict__ g,
    const float* __restrict__ bvec, float* __restrict__ ab, int Ncols, float invM)
{
    int c = blockIdx.x * 256 + threadIdx.x;
    if (c >= Ncols) return;
    float mean = sums[c] * invM;
    float var  = sums[Ncols + c] * invM - mean * mean;
    float a    = g[c] * rsqrtf(var + 1e-5f);
    ab[c] = a;
    ab[Ncols + c] = bvec[c] - mean * a;
}

__global__ __launch_bounds__(256) void bn_apply_k(
    float* __restrict__ Z, const float* __restrict__ ab, int Ncols, int total4)
{
    for (int i4 = blockIdx.x * 256 + threadIdx.x; i4 < total4; i4 += gridDim.x * 256) {
        int col = (i4 * 4) % Ncols;
        float4 z  = *(float4*)(Z + (size_t)i4 * 4);
        float4 a4 = *(const float4*)(ab + col);
        float4 b4 = *(const float4*)(ab + Ncols + col);
        z.x = a4.x * z.x + b4.x; z.y = a4.y * z.y + b4.y;
        z.z = a4.z * z.z + b4.z; z.w = a4.w * z.w + b4.w;
        *(float4*)(Z + (size_t)i4 * 4) = z;
    }
}

__global__ __launch_bounds__(256) void bn_apply_bf16_k(
    u16* __restrict__ Z, const float* __restrict__ ab, int Ncols, int total8)
{
    int i8 = blockIdx.x * 256 + threadIdx.x;
    if (i8 >= total8) return;
    int col = (i8 * 8) % Ncols;
    uint4 u = *(uint4*)(Z + (size_t)i8 * 8);
    float4 A0 = *(const float4*)(ab + col),         A1 = *(const float4*)(ab + col + 4);
    float4 B0 = *(const float4*)(ab + Ncols + col), B1 = *(const float4*)(ab + Ncols + col + 4);
    uint4 o;
    o.x = pk2(fmaf(b2f((u16)(u.x & 0xffff)), A0.x, B0.x), fmaf(b2f((u16)(u.x >> 16)), A0.y, B0.y));
    o.y = pk2(fmaf(b2f((u16)(u.y & 0xffff)), A0.z, B0.z), fmaf(b2f((u16)(u.y >> 16)), A0.w, B0.w));
    o.z = pk2(fmaf(b2f((u16)(u.z & 0xffff)), A1.x, B1.x), fmaf(b2f((u16)(u.z >> 16)), A1.y, B1.y));
    o.w = pk2(fmaf(b2f((u16)(u.w & 0xffff)), A1.z, B1.z), fmaf(b2f((u16)(u.w >> 16)), A1.w, B1.w));
    *(uint4*)(Z + (size_t)i8 * 8) = o;
}

// ---------------------------------------------------------------- MFMA flash attention v4
// 128-q blocks (2 q-subtiles per wave): K loads + V staging amortized 2x, half the blocks.
// Operand-swapped S^T = K*Q^T; K register-prefetched (depth-1) like V; vt double-buffered.
__global__ __launch_bounds__(256) void attn_mfma_k(
    const u16* __restrict__ Y,
    const float* __restrict__ biases, const int* __restrict__ idxs,
    u16* __restrict__ O)
{
    __shared__ u16 vt[2][6 * 64 * 8];       // double-buffered V^T, frag-order (12 KB)
    __shared__ u16 psm[4][2][2 * 64 * 8];   // per-wave, per-q-half P^T (16 KB)
    __shared__ float hb[NTOK];

    const int t = threadIdx.x;
    const int lane = t & 63, wv = t >> 6;
    const int l15 = lane & 15, quad = lane >> 4;
    const int bh = blockIdx.x;
    const int b = bh >> 3, h = bh & 7;
    const int n0 = blockIdx.y * 128;
    const int bN = b * NTOK;
    const int colQ = h * HDIM, colK = CDIM + colQ, colV = 2 * CDIM + colQ;
    const floatx4 zf = {0.f, 0.f, 0.f, 0.f};

    if (t < 196) *(float4*)&hb[t << 2] = *(const float4*)(biases + (size_t)h * NTOK + (t << 2));

    int qv[2], qr[2];
    #pragma unroll
    for (int qh = 0; qh < 2; qh++) {
        qv[qh] = n0 + qh * 64 + wv * 16 + l15;
        qr[qh] = qv[qh] < NTOK ? qv[qh] : NTOK - 1;
    }

    // Q B-frags: B[k=d][n=q=l15]; chunk1 zero for quad>=2 (d pad 48..63)
    short8 qf[2][2];
    #pragma unroll
    for (int qh = 0; qh < 2; qh++) {
        V8 a0, a1;
        a1.u = make_uint4(0u, 0u, 0u, 0u);
        const u16* src = Y + (size_t)(bN + qr[qh]) * INNER + colQ;
        a0.u = *(const uint4*)(src + quad * 8);
        if (quad < 2) a1.u = *(const uint4*)(src + 32 + quad * 8);
        qf[qh][0] = a0.s; qf[qh][1] = a1.s;
    }

    // V staging items: item f -> key r=f/6, seg s=f%6; frag-order scatter dests
    const int r0 = t / 6,         s0 = t % 6;
    const int r1 = (256 + t) / 6, s1 = (256 + t) % 6;
    const bool own1 = (t < 128);
    const int vbase0 = (((s0 >> 1) * 2 + (r0 >> 5)) * 64 + ((r0 & 31) >> 3) * 16 + (s0 & 1) * 8) * 8 + (r0 & 7);
    const int vbase1 = (((s1 >> 1) * 2 + (r1 >> 5)) * 64 + ((r1 & 31) >> 3) * 16 + (s1 & 1) * 8) * 8 + (r1 & 7);

    // preload V tile 0 -> vt[0]
    V8 pv0, pv1;
    pv0.u = *(const uint4*)(Y + (size_t)(bN + r0) * INNER + colV + s0 * 8);
    if (own1) pv1.u = *(const uint4*)(Y + (size_t)(bN + r1) * INNER + colV + s1 * 8);
    {
        u16* vtb = vt[0];
        #pragma unroll
        for (int j = 0; j < 8; j++) vtb[vbase0 + j * 8] = pv0.h[j];
        if (own1) {
            #pragma unroll
            for (int j = 0; j < 8; j++) vtb[vbase1 + j * 8] = pv1.h[j];
        }
    }

    // preload K A-frags for tile 0 (keys 0..63 all valid)
    V8 kfr[4][2];
    #pragma unroll
    for (int sub = 0; sub < 4; sub++) {
        const u16* src = Y + (size_t)(bN + sub * 16 + l15) * INNER + colK;
        kfr[sub][0].u = *(const uint4*)(src + quad * 8);
        kfr[sub][1].u = *(const uint4*)(src + 32 + quad * 8);
    }

    float lsum[2] = {0.f, 0.f};
    floatx4 oacc[2][3];
    #pragma unroll
    for (int qh = 0; qh < 2; qh++)
        #pragma unroll
        for (int i = 0; i < 3; i++) oacc[qh][i] = zf;

    const int* idxrow[2] = { idxs + (size_t)qr[0] * NTOK, idxs + (size_t)qr[1] * NTOK };
    const int psbase = ((quad >> 1) * 16 + l15) * 8 + (quad & 1) * 4;

    for (int mt = 0; mt < 13; mt++) {
        const int m0k = mt * 64;
        __syncthreads();   // vt[mt&1] fully staged; hb/psm fenced at mt=0

        // ---- prefetch K(mt+1) and V(mt+1) into regs (consumed next iter / later this iter)
        V8 kn[4][2];
        const bool more = (mt + 1 < 13);
        if (more) {
            const int mn = m0k + 64;
            #pragma unroll
            for (int sub = 0; sub < 4; sub++) {
                int key = mn + sub * 16 + l15;
                int kr  = key < NTOK ? key : NTOK - 1;
                const u16* src = Y + (size_t)(bN + kr) * INNER + colK;
                kn[sub][0].u = *(const uint4*)(src + quad * 8);
                kn[sub][1].u = *(const uint4*)(src + 32 + quad * 8);
            }
            int k0v = mn + r0; k0v = k0v < NTOK ? k0v : NTOK - 1;
            pv0.u = *(const uint4*)(Y + (size_t)(bN + k0v) * INNER + colV + s0 * 8);
            if (own1) {
                int k1v = mn + r1; k1v = k1v < NTOK ? k1v : NTOK - 1;
                pv1.u = *(const uint4*)(Y + (size_t)(bN + k1v) * INNER + colV + s1 * 8);
            }
        }

        // ---- per q-half: S^T = K*Q^T, then exp + P^T -> psm
        #pragma unroll
        for (int qh = 0; qh < 2; qh++) {
            floatx4 sf[4];
            #pragma unroll
            for (int sub = 0; sub < 4; sub++) {
                floatx4 c = zf;
                c = __builtin_amdgcn_mfma_f32_16x16x32_bf16(kfr[sub][0].s, qf[qh][0], c, 0, 0, 0);
                c = __builtin_amdgcn_mfma_f32_16x16x32_bf16(kfr[sub][1].s, qf[qh][1], c, 0, 0, 0);
                sf[sub] = c;
            }
            #pragma unroll
            for (int sub = 0; sub < 4; sub++) {
                int kb  = m0k + sub * 16 + quad * 4;
                int kbc = kb <= NTOK - 4 ? kb : NTOK - 4;
                int4 iv = *(const int4*)(idxrow[qh] + kbc);
                float pr[4];
                #pragma unroll
                for (int reg = 0; reg < 4; reg++) {
                    int key = kb + reg;
                    int ivr = (reg == 0) ? iv.x : (reg == 1) ? iv.y : (reg == 2) ? iv.z : iv.w;
                    float p = 0.f;
                    if (key < NTOK)
                        p = __expf(fmaf(sf[sub][reg], SCALE, hb[ivr]));
                    pr[reg] = p;
                    lsum[qh] += p;
                }
                int addr = psbase + (sub >> 1) * 512 + (sub & 1) * 256;
                *(uint2*)&psm[wv][qh][addr] = make_uint2(pk2(pr[0], pr[1]), pk2(pr[2], pr[3]));
            }
        }

        // ---- stage vt for next tile
        if (more) {
            u16* vtb = vt[(mt + 1) & 1];
            #pragma unroll
            for (int j = 0; j < 8; j++) vtb[vbase0 + j * 8] = pv0.h[j];
            if (own1) {
                #pragma unroll
                for (int j = 0; j < 8; j++) vtb[vbase1 + j * 8] = pv1.h[j];
            }
        }

        // ---- O^T += V^T * P^T (V frags shared across q-halves)
        const u16* vtb = vt[mt & 1];
        #pragma unroll
        for (int kc = 0; kc < 2; kc++) {
            short8 pb0 = *(const short8*)&psm[wv][0][(kc * 64 + lane) * 8];
            short8 pb1 = *(const short8*)&psm[wv][1][(kc * 64 + lane) * 8];
            #pragma unroll
            for (int ns = 0; ns < 3; ns++) {
                short8 va = *(const short8*)&vtb[((ns * 2 + kc) * 64 + lane) * 8];
                oacc[0][ns] = __builtin_amdgcn_mfma_f32_16x16x32_bf16(va, pb0, oacc[0][ns], 0, 0, 0);
                oacc[1][ns] = __builtin_amdgcn_mfma_f32_16x16x32_bf16(va, pb1, oacc[1][ns], 0, 0, 0);
            }
        }

        // ---- rotate K pipeline
        if (more) {
            #pragma unroll
            for (int sub = 0; sub < 4; sub++) {
                kfr[sub][0] = kn[sub][0];
                kfr[sub][1] = kn[sub][1];
            }
        }
    }

    // ---- epilogue
    #pragma unroll
    for (int qh = 0; qh < 2; qh++) {
        float ls = lsum[qh];
        ls += __shfl_xor(ls, 16);
        ls += __shfl_xor(ls, 32);
        if (qv[qh] < NTOK) {
            float rl = 1.f / ls;
            u16* dst = O + (size_t)(bN + qv[qh]) * CDIM + colQ;
            #pragma unroll
            for (int ns = 0; ns < 3; ns++)
                #pragma unroll
                for (int reg = 0; reg < 4; reg++)
                    dst[ns * 16 + quad * 4 + reg] = f2b(hswish_f(oacc[qh][ns][reg] * rl));
        }
    }
}

// ---------------------------------------------------------------- launch
extern "C" void kernel_launch(void* const* d_in, const int* in_sizes, int n_in,
                              void* d_out, int out_size, void* d_ws, size_t ws_size,
                              hipStream_t stream)
{
    const float* x     = (const float*)d_in[0];
    const float* Wqkv  = (const float*)d_in[1];
    const float* g1    = (const float*)d_in[2];
    const float* b1    = (const float*)d_in[3];
    const float* Wproj = (const float*)d_in[4];
    const float* g2    = (const float*)d_in[5];
    const float* b2    = (const float*)d_in[6];
    const float* bias  = (const float*)d_in[7];
    const int*   idxs  = (const int*)d_in[8];
    float* out = (float*)d_out;
    char*  wsb = (char*)d_ws;

    u16*   Yb  = (u16*)wsb;
    u16*   Ob  = (u16*)(wsb + OB_OFF);
    float* S1  = (float*)(wsb + ST_OFF);
    float* AB1 = S1 + 2304;
    float* S2  = AB1 + 2304;
    float* AB2 = S2 + 768;

    zero_k<<<24, 256, 0, stream>>>(S1, 6144);

    // GEMM1 (+fused BN1 stats): Ybf16 = x @ Wqkv^T
    gemm_mfma_k<0, 0, 1><<<dim3(INNER / 128, R_TOTAL / 128), 256, 0, stream>>>(
        x, Wqkv, Yb, S1, R_TOTAL, INNER, CDIM);

    finalize_bn_k<<<(INNER + 255) / 256, 256, 0, stream>>>(S1, g1, b1, AB1, INNER, 1.f / R_TOTAL);
    bn_apply_bf16_k<<<(R_TOTAL * INNER / 8 + 255) / 256, 256, 0, stream>>>(
        Yb, AB1, INNER, R_TOTAL * INNER / 8);

    // attention: 128-q blocks, K+V prefetch pipeline
    attn_mfma_k<<<dim3(NHEAD * BATCH, 7), 256, 0, stream>>>(Yb, bias, idxs, Ob);

    // GEMM2 (+fused BN2 stats): out = O_hsw @ Wproj^T
    gemm_mfma_k<1, 0, 0><<<dim3(CDIM / 128, R_TOTAL / 128), 256, 0, stream>>>(
        Ob, Wproj, out, S2, R_TOTAL, CDIM, CDIM);

    finalize_bn_k<<<(CDIM + 255) / 256, 256, 0, stream>>>(S2, g2, b2, AB2, CDIM, 1.f / R_TOTAL);
    bn_apply_k<<<1024, 256, 0, stream>>>(out, AB2, CDIM, (R_TOTAL * CDIM) / 4);
}

// Round 8
// 259.489 us; speedup vs baseline: 1.3396x; 1.0113x over previous
//
#include <hip/hip_runtime.h>

#define R_TOTAL 12544
#define NTOK    784
#define CDIM    384
#define INNER   1152
#define NHEAD   8
#define HDIM    48
#define BATCH   16
#define SCALE   0.14433756729740643f   // 48^-0.5
#define INV28   0.035714287f           // fp32(1/28) rounds UP -> floor(key*INV28)==key/28 for key<=783

typedef unsigned short u16;
typedef unsigned int   u32;
typedef __attribute__((ext_vector_type(8))) short short8;   // 8 bf16, 4 VGPRs
typedef __attribute__((ext_vector_type(4))) float floatx4;  // MFMA C/D

union V8 { uint4 u; short8 s; u16 h[8]; };

// workspace layout (BYTE offsets) — total 38.56 MB, byte-identical to rounds 2-7 (proven safe).
#define OB_OFF     28901376ull   // Yb bf16 [12544,1152] at 0; Ob bf16 [12544,384] here
#define ST_OFF     38535168ull   // fp32 stats: S1[2304] AB1[2304] S2[768] AB2[768]

__device__ __forceinline__ float b2f(u16 u) {
    union { float f; u32 i; } v; v.i = ((u32)u) << 16; return v.f;
}
__device__ __forceinline__ u16 f2b(float f) {
    union { float f; u32 i; } v; v.f = f;
    u32 r = v.i + 0x7FFFu + ((v.i >> 16) & 1u);   // RNE
    return (u16)(r >> 16);
}
__device__ __forceinline__ u32 pk2(float lo, float hi) {
    return (u32)f2b(lo) | ((u32)f2b(hi) << 16);
}
__device__ __forceinline__ float hswish_f(float v) {
    return v * fminf(fmaxf(v + 3.f, 0.f), 6.f) * (1.f / 6.f);
}

__global__ __launch_bounds__(256) void zero_k(float* __restrict__ p, int n) {
    int i = blockIdx.x * 256 + threadIdx.x;
    if (i < n) p[i] = 0.f;
}

// ---------------------------------------------------------------- MFMA GEMM (+fused BN col stats)
template<int ABF16, int HSW, int OBF16>
__global__ __launch_bounds__(256) void gemm_mfma_k(
    const void* __restrict__ Ap, const float* __restrict__ Bfp,
    void* __restrict__ Cp, float* __restrict__ sums, int M, int Nout, int K)
{
    __shared__ u16 As[128 * 40];
    __shared__ u16 Bs[128 * 40];
    const int t = threadIdx.x;
    const int lane = t & 63, wv = t >> 6;
    const int l15 = lane & 15, quad = lane >> 4;
    const int wm = (wv & 1) * 64, wn = (wv >> 1) * 64;
    const int m0 = blockIdx.y * 128, n0 = blockIdx.x * 128;
    const floatx4 zf = {0.f, 0.f, 0.f, 0.f};

    floatx4 acc[4][4];
    #pragma unroll
    for (int i = 0; i < 4; i++)
        #pragma unroll
        for (int j = 0; j < 4; j++) acc[i][j] = zf;

    for (int k0 = 0; k0 < K; k0 += 32) {
        __syncthreads();
        #pragma unroll
        for (int it = 0; it < 2; it++) {
            const int flat = t + it * 256;
            const int rr = flat >> 2, ss = (flat & 3) * 8;
            uint4 aw;
            if (ABF16) {
                uint4 u = *(const uint4*)((const u16*)Ap + (size_t)(m0 + rr) * K + k0 + ss);
                if (HSW) {
                    aw.x = pk2(hswish_f(b2f((u16)(u.x & 0xffff))), hswish_f(b2f((u16)(u.x >> 16))));
                    aw.y = pk2(hswish_f(b2f((u16)(u.y & 0xffff))), hswish_f(b2f((u16)(u.y >> 16))));
                    aw.z = pk2(hswish_f(b2f((u16)(u.z & 0xffff))), hswish_f(b2f((u16)(u.z >> 16))));
                    aw.w = pk2(hswish_f(b2f((u16)(u.w & 0xffff))), hswish_f(b2f((u16)(u.w >> 16))));
                } else {
                    aw = u;
                }
            } else {
                const float* p = (const float*)Ap + (size_t)(m0 + rr) * K + k0 + ss;
                float4 f0 = *(const float4*)p, f1 = *(const float4*)(p + 4);
                aw.x = pk2(f0.x, f0.y); aw.y = pk2(f0.z, f0.w);
                aw.z = pk2(f1.x, f1.y); aw.w = pk2(f1.z, f1.w);
            }
            *(uint4*)&As[rr * 40 + ss] = aw;
            const float* q = Bfp + (size_t)(n0 + rr) * K + k0 + ss;
            float4 g0 = *(const float4*)q, g1 = *(const float4*)(q + 4);
            uint4 bw;
            bw.x = pk2(g0.x, g0.y); bw.y = pk2(g0.z, g0.w);
            bw.z = pk2(g1.x, g1.y); bw.w = pk2(g1.z, g1.w);
            *(uint4*)&Bs[rr * 40 + ss] = bw;
        }
        __syncthreads();
        short8 af[4], bfr[4];
        #pragma unroll
        for (int mi = 0; mi < 4; mi++)
            af[mi] = *(const short8*)&As[(wm + mi * 16 + l15) * 40 + quad * 8];
        #pragma unroll
        for (int ni = 0; ni < 4; ni++)
            bfr[ni] = *(const short8*)&Bs[(wn + ni * 16 + l15) * 40 + quad * 8];
        #pragma unroll
        for (int mi = 0; mi < 4; mi++)
            #pragma unroll
            for (int ni = 0; ni < 4; ni++)
                acc[mi][ni] = __builtin_amdgcn_mfma_f32_16x16x32_bf16(af[mi], bfr[ni], acc[mi][ni], 0, 0, 0);
    }

    float cs[4] = {0.f, 0.f, 0.f, 0.f}, cq[4] = {0.f, 0.f, 0.f, 0.f};
    #pragma unroll
    for (int mi = 0; mi < 4; mi++) {
        const int mbase = m0 + wm + mi * 16 + quad * 4;
        #pragma unroll
        for (int ni = 0; ni < 4; ni++) {
            const int n = n0 + wn + ni * 16 + l15;
            #pragma unroll
            for (int reg = 0; reg < 4; reg++) {
                size_t off = (size_t)(mbase + reg) * Nout + n;
                float v = acc[mi][ni][reg];
                float vv;
                if (OBF16) {
                    u16 hv = f2b(v);
                    ((u16*)Cp)[off] = hv;
                    vv = b2f(hv);
                } else {
                    ((float*)Cp)[off] = v;
                    vv = v;
                }
                cs[ni] += vv;
                cq[ni] += vv * vv;
            }
        }
    }
    #pragma unroll
    for (int ni = 0; ni < 4; ni++) {
        float s = cs[ni], sq = cq[ni];
        s  += __shfl_xor(s, 16);  s  += __shfl_xor(s, 32);
        sq += __shfl_xor(sq, 16); sq += __shfl_xor(sq, 32);
        if (quad == 0) {
            int col = n0 + wn + ni * 16 + l15;
            atomicAdd(&sums[col], s);
            atomicAdd(&sums[Nout + col], sq);
        }
    }
}

__global__ __launch_bounds__(256) void finalize_bn_k(
    const float* __restrict__ sums, const float* __restrict__ g,
    const float* __restrict__ bvec, float* __restrict__ ab, int Ncols, float invM)
{
    int c = blockIdx.x * 256 + threadIdx.x;
    if (c >= Ncols) return;
    float mean = sums[c] * invM;
    float var  = sums[Ncols + c] * invM - mean * mean;
    float a    = g[c] * rsqrtf(var + 1e-5f);
    ab[c] = a;
    ab[Ncols + c] = bvec[c] - mean * a;
}

__global__ __launch_bounds__(256) void bn_apply_k(
    float* __restrict__ Z, const float* __restrict__ ab, int Ncols, int total4)
{
    for (int i4 = blockIdx.x * 256 + threadIdx.x; i4 < total4; i4 += gridDim.x * 256) {
        int col = (i4 * 4) % Ncols;
        float4 z  = *(float4*)(Z + (size_t)i4 * 4);
        float4 a4 = *(const float4*)(ab + col);
        float4 b4 = *(const float4*)(ab + Ncols + col);
        z.x = a4.x * z.x + b4.x; z.y = a4.y * z.y + b4.y;
        z.z = a4.z * z.z + b4.z; z.w = a4.w * z.w + b4.w;
        *(float4*)(Z + (size_t)i4 * 4) = z;
    }
}

__global__ __launch_bounds__(256) void bn_apply_bf16_k(
    u16* __restrict__ Z, const float* __restrict__ ab, int Ncols, int total8)
{
    int i8 = blockIdx.x * 256 + threadIdx.x;
    if (i8 >= total8) return;
    int col = (i8 * 8) % Ncols;
    uint4 u = *(uint4*)(Z + (size_t)i8 * 8);
    float4 A0 = *(const float4*)(ab + col),         A1 = *(const float4*)(ab + col + 4);
    float4 B0 = *(const float4*)(ab + Ncols + col), B1 = *(const float4*)(ab + Ncols + col + 4);
    uint4 o;
    o.x = pk2(fmaf(b2f((u16)(u.x & 0xffff)), A0.x, B0.x), fmaf(b2f((u16)(u.x >> 16)), A0.y, B0.y));
    o.y = pk2(fmaf(b2f((u16)(u.y & 0xffff)), A0.z, B0.z), fmaf(b2f((u16)(u.y >> 16)), A0.w, B0.w));
    o.z = pk2(fmaf(b2f((u16)(u.z & 0xffff)), A1.x, B1.x), fmaf(b2f((u16)(u.z >> 16)), A1.y, B1.y));
    o.w = pk2(fmaf(b2f((u16)(u.w & 0xffff)), A1.z, B1.z), fmaf(b2f((u16)(u.w >> 16)), A1.w, B1.w));
    *(uint4*)(Z + (size_t)i8 * 8) = o;
}

// 8x8 u16 transpose across 8 lanes (g = lane&7) via 3 butterfly stages.
// In: lane g holds row g (8 u16 = keys fixed, d varying). Out: lane g holds column g
// (d fixed = g, 8 consecutive keys) — exactly one frag-order b128 slot.
__device__ __forceinline__ uint4 transpose8x8_u16(uint4 v, int g) {
    u32 r0 = v.x, r1 = v.y, r2 = v.z, r3 = v.w;
    // stage d=4: t_k = shfl_xor(r[k^2],4); keep if ((k>>1)&1)==((g>>2)&1)
    {
        u32 t0 = (u32)__shfl_xor((int)r2, 4);
        u32 t1 = (u32)__shfl_xor((int)r3, 4);
        u32 t2 = (u32)__shfl_xor((int)r0, 4);
        u32 t3 = (u32)__shfl_xor((int)r1, 4);
        bool gb2 = (g >> 2) & 1;
        r0 = gb2 ? t0 : r0;
        r1 = gb2 ? t1 : r1;
        r2 = gb2 ? r2 : t2;
        r3 = gb2 ? r3 : t3;
    }
    // stage d=2: t_k = shfl_xor(r[k^1],2); keep if (k&1)==((g>>1)&1)
    {
        u32 t0 = (u32)__shfl_xor((int)r1, 2);
        u32 t1 = (u32)__shfl_xor((int)r0, 2);
        u32 t2 = (u32)__shfl_xor((int)r3, 2);
        u32 t3 = (u32)__shfl_xor((int)r2, 2);
        bool gb1 = (g >> 1) & 1;
        r0 = gb1 ? t0 : r0;
        r1 = gb1 ? r1 : t1;
        r2 = gb1 ? t2 : r2;
        r3 = gb1 ? r3 : t3;
    }
    // stage d=1: sub-word swap with partner lane
    {
        u32 t0 = (u32)__shfl_xor((int)r0, 1);
        u32 t1 = (u32)__shfl_xor((int)r1, 1);
        u32 t2 = (u32)__shfl_xor((int)r2, 1);
        u32 t3 = (u32)__shfl_xor((int)r3, 1);
        if (g & 1) {
            r0 = (r0 & 0xFFFF0000u) | (t0 >> 16);
            r1 = (r1 & 0xFFFF0000u) | (t1 >> 16);
            r2 = (r2 & 0xFFFF0000u) | (t2 >> 16);
            r3 = (r3 & 0xFFFF0000u) | (t3 >> 16);
        } else {
            r0 = (r0 & 0x0000FFFFu) | (t0 << 16);
            r1 = (r1 & 0x0000FFFFu) | (t1 << 16);
            r2 = (r2 & 0x0000FFFFu) | (t2 << 16);
            r3 = (r3 & 0x0000FFFFu) | (t3 << 16);
        }
    }
    return make_uint4(r0, r1, r2, r3);
}

// ---------------------------------------------------------------- MFMA flash attention v5
// 128-q blocks, swapped S^T=K*Q^T, K+V depth-1 reg prefetch, vt double-buffered.
// V staged via in-register 8x8 transpose -> conflict-free b128 frag-order writes.
// Rel-pos bias index computed arithmetically (no idxs loads).
__global__ __launch_bounds__(256) void attn_mfma_k(
    const u16* __restrict__ Y,
    const float* __restrict__ biases,
    u16* __restrict__ O)
{
    __shared__ u16 vt[2][6 * 64 * 8];       // double-buffered V^T, frag-order (12 KB)
    __shared__ u16 psm[4][2][2 * 64 * 8];   // per-wave, per-q-half P^T (16 KB)
    __shared__ float hb[NTOK];

    const int t = threadIdx.x;
    const int lane = t & 63, wv = t >> 6;
    const int l15 = lane & 15, quad = lane >> 4;
    const int g8 = lane & 7, sg = lane >> 3;
    const int bh = blockIdx.x;
    const int b = bh >> 3, h = bh & 7;
    const int n0 = blockIdx.y * 128;
    const int bN = b * NTOK;
    const int colQ = h * HDIM, colK = CDIM + colQ, colV = 2 * CDIM + colQ;
    const floatx4 zf = {0.f, 0.f, 0.f, 0.f};

    if (t < 196) *(float4*)&hb[t << 2] = *(const float4*)(biases + (size_t)h * NTOK + (t << 2));

    int qv[2], qr[2], xi[2], yi[2];
    #pragma unroll
    for (int qh = 0; qh < 2; qh++) {
        qv[qh] = n0 + qh * 64 + wv * 16 + l15;
        qr[qh] = qv[qh] < NTOK ? qv[qh] : NTOK - 1;
        xi[qh] = (int)((float)qr[qh] * INV28);
        yi[qh] = qr[qh] - 28 * xi[qh];
    }

    // Q B-frags: B[k=d][n=q=l15]; chunk1 zero for quad>=2 (d pad 48..63)
    short8 qf[2][2];
    #pragma unroll
    for (int qh = 0; qh < 2; qh++) {
        V8 a0, a1;
        a1.u = make_uint4(0u, 0u, 0u, 0u);
        const u16* src = Y + (size_t)(bN + qr[qh]) * INNER + colQ;
        a0.u = *(const uint4*)(src + quad * 8);
        if (quad < 2) a1.u = *(const uint4*)(src + 32 + quad * 8);
        qf[qh][0] = a0.s; qf[qh][1] = a1.s;
    }

    // V staging v2: wave wv stages d-seg wv (pass A) and 4+wv for wv<2 (pass B).
    // Lane loads V[key=m0k+lane][dseg*8..+7], 8x8-transposes within its 8-lane group,
    // writes one b128 frag-order slot: d = ds*8+g8, keys (sg*8..+7).
    const bool ownB = (wv < 2);
    const int dsA = wv, dsB = 4 + wv;
    // write addrs (u16 index): region = (d>>4)*2 + (sg>>2); lane_in = (sg&3)*16 + (d&15)
    const int dA = dsA * 8 + g8, dB = dsB * 8 + g8;
    const int vaddrA = (((dA >> 4) * 2 + (sg >> 2)) * 64 + (sg & 3) * 16 + (dA & 15)) * 8;
    const int vaddrB = (((dB >> 4) * 2 + (sg >> 2)) * 64 + (sg & 3) * 16 + (dB & 15)) * 8;

    V8 pvA, pvB;
    {   // preload V tile 0 (keys 0..63 all valid) and stage vt[0]
        const u16* src = Y + (size_t)(bN + lane) * INNER + colV;
        pvA.u = *(const uint4*)(src + dsA * 8);
        if (ownB) pvB.u = *(const uint4*)(src + dsB * 8);
        *(uint4*)&vt[0][vaddrA] = transpose8x8_u16(pvA.u, g8);
        if (ownB) *(uint4*)&vt[0][vaddrB] = transpose8x8_u16(pvB.u, g8);
    }

    // preload K A-frags for tile 0
    V8 kfr[4][2];
    #pragma unroll
    for (int sub = 0; sub < 4; sub++) {
        const u16* src = Y + (size_t)(bN + sub * 16 + l15) * INNER + colK;
        kfr[sub][0].u = *(const uint4*)(src + quad * 8);
        kfr[sub][1].u = *(const uint4*)(src + 32 + quad * 8);
    }

    float lsum[2] = {0.f, 0.f};
    floatx4 oacc[2][3];
    #pragma unroll
    for (int qh = 0; qh < 2; qh++)
        #pragma unroll
        for (int i = 0; i < 3; i++) oacc[qh][i] = zf;

    const int psbase = ((quad >> 1) * 16 + l15) * 8 + (quad & 1) * 4;

    for (int mt = 0; mt < 13; mt++) {
        const int m0k = mt * 64;
        __syncthreads();   // vt[mt&1] fully staged; hb/psm fenced at mt=0

        // ---- prefetch K(mt+1), V(mt+1) into regs
        V8 kn[4][2];
        const bool more = (mt + 1 < 13);
        if (more) {
            const int mn = m0k + 64;
            #pragma unroll
            for (int sub = 0; sub < 4; sub++) {
                int key = mn + sub * 16 + l15;
                int kr  = key < NTOK ? key : NTOK - 1;
                const u16* src = Y + (size_t)(bN + kr) * INNER + colK;
                kn[sub][0].u = *(const uint4*)(src + quad * 8);
                kn[sub][1].u = *(const uint4*)(src + 32 + quad * 8);
            }
            int kv = mn + lane; kv = kv < NTOK ? kv : NTOK - 1;
            const u16* src = Y + (size_t)(bN + kv) * INNER + colV;
            pvA.u = *(const uint4*)(src + dsA * 8);
            if (ownB) pvB.u = *(const uint4*)(src + dsB * 8);
        }

        // ---- per q-half: S^T = K*Q^T, then exp + P^T -> psm (bias via arithmetic index)
        #pragma unroll
        for (int qh = 0; qh < 2; qh++) {
            floatx4 sf[4];
            #pragma unroll
            for (int sub = 0; sub < 4; sub++) {
                floatx4 c = zf;
                c = __builtin_amdgcn_mfma_f32_16x16x32_bf16(kfr[sub][0].s, qf[qh][0], c, 0, 0, 0);
                c = __builtin_amdgcn_mfma_f32_16x16x32_bf16(kfr[sub][1].s, qf[qh][1], c, 0, 0, 0);
                sf[sub] = c;
            }
            #pragma unroll
            for (int sub = 0; sub < 4; sub++) {
                int kb = m0k + sub * 16 + quad * 4;
                float pr[4];
                #pragma unroll
                for (int reg = 0; reg < 4; reg++) {
                    int key = kb + reg;
                    int xk = (int)((float)key * INV28);
                    int yk = key - 28 * xk;
                    int dx = xi[qh] - xk; dx = dx < 0 ? -dx : dx;
                    int dy = yi[qh] - yk; dy = dy < 0 ? -dy : dy;
                    float p = 0.f;
                    if (key < NTOK)
                        p = __expf(fmaf(sf[sub][reg], SCALE, hb[dx * 28 + dy]));
                    pr[reg] = p;
                    lsum[qh] += p;
                }
                int addr = psbase + (sub >> 1) * 512 + (sub & 1) * 256;
                *(uint2*)&psm[wv][qh][addr] = make_uint2(pk2(pr[0], pr[1]), pk2(pr[2], pr[3]));
            }
        }

        // ---- stage vt for next tile (transpose prefetched regs, b128 conflict-free)
        if (more) {
            u16* vtb = vt[(mt + 1) & 1];
            *(uint4*)&vtb[vaddrA] = transpose8x8_u16(pvA.u, g8);
            if (ownB) *(uint4*)&vtb[vaddrB] = transpose8x8_u16(pvB.u, g8);
        }

        // ---- O^T += V^T * P^T (V frags shared across q-halves)
        const u16* vtb = vt[mt & 1];
        #pragma unroll
        for (int kc = 0; kc < 2; kc++) {
            short8 pb0 = *(const short8*)&psm[wv][0][(kc * 64 + lane) * 8];
            short8 pb1 = *(const short8*)&psm[wv][1][(kc * 64 + lane) * 8];
            #pragma unroll
            for (int ns = 0; ns < 3; ns++) {
                short8 va = *(const short8*)&vtb[((ns * 2 + kc) * 64 + lane) * 8];
                oacc[0][ns] = __builtin_amdgcn_mfma_f32_16x16x32_bf16(va, pb0, oacc[0][ns], 0, 0, 0);
                oacc[1][ns] = __builtin_amdgcn_mfma_f32_16x16x32_bf16(va, pb1, oacc[1][ns], 0, 0, 0);
            }
        }

        // ---- rotate K pipeline
        if (more) {
            #pragma unroll
            for (int sub = 0; sub < 4; sub++) {
                kfr[sub][0] = kn[sub][0];
                kfr[sub][1] = kn[sub][1];
            }
        }
    }

    // ---- epilogue
    #pragma unroll
    for (int qh = 0; qh < 2; qh++) {
        float ls = lsum[qh];
        ls += __shfl_xor(ls, 16);
        ls += __shfl_xor(ls, 32);
        if (qv[qh] < NTOK) {
            float rl = 1.f / ls;
            u16* dst = O + (size_t)(bN + qv[qh]) * CDIM + colQ;
            #pragma unroll
            for (int ns = 0; ns < 3; ns++)
                #pragma unroll
                for (int reg = 0; reg < 4; reg++)
                    dst[ns * 16 + quad * 4 + reg] = f2b(hswish_f(oacc[qh][ns][reg] * rl));
        }
    }
}

// ---------------------------------------------------------------- launch
extern "C" void kernel_launch(void* const* d_in, const int* in_sizes, int n_in,
                              void* d_out, int out_size, void* d_ws, size_t ws_size,
                              hipStream_t stream)
{
    const float* x     = (const float*)d_in[0];
    const float* Wqkv  = (const float*)d_in[1];
    const float* g1    = (const float*)d_in[2];
    const float* b1    = (const float*)d_in[3];
    const float* Wproj = (const float*)d_in[4];
    const float* g2    = (const float*)d_in[5];
    const float* b2    = (const float*)d_in[6];
    const float* bias  = (const float*)d_in[7];
    float* out = (float*)d_out;
    char*  wsb = (char*)d_ws;

    u16*   Yb  = (u16*)wsb;
    u16*   Ob  = (u16*)(wsb + OB_OFF);
    float* S1  = (float*)(wsb + ST_OFF);
    float* AB1 = S1 + 2304;
    float* S2  = AB1 + 2304;
    float* AB2 = S2 + 768;

    zero_k<<<24, 256, 0, stream>>>(S1, 6144);

    // GEMM1 (+fused BN1 stats): Ybf16 = x @ Wqkv^T
    gemm_mfma_k<0, 0, 1><<<dim3(INNER / 128, R_TOTAL / 128), 256, 0, stream>>>(
        x, Wqkv, Yb, S1, R_TOTAL, INNER, CDIM);

    finalize_bn_k<<<(INNER + 255) / 256, 256, 0, stream>>>(S1, g1, b1, AB1, INNER, 1.f / R_TOTAL);
    bn_apply_bf16_k<<<(R_TOTAL * INNER / 8 + 255) / 256, 256, 0, stream>>>(
        Yb, AB1, INNER, R_TOTAL * INNER / 8);

    // attention: 128-q blocks, K+V prefetch, transpose-staged V, arithmetic bias index
    attn_mfma_k<<<dim3(NHEAD * BATCH, 7), 256, 0, stream>>>(Yb, bias, Ob);

    // GEMM2 (+fused BN2 stats): out = O_hsw @ Wproj^T
    gemm_mfma_k<1, 0, 0><<<dim3(CDIM / 128, R_TOTAL / 128), 256, 0, stream>>>(
        Ob, Wproj, out, S2, R_TOTAL, CDIM, CDIM);

    finalize_bn_k<<<(CDIM + 255) / 256, 256, 0, stream>>>(S2, g2, b2, AB2, CDIM, 1.f / R_TOTAL);
    bn_apply_k<<<1024, 256, 0, stream>>>(out, AB2, CDIM, (R_TOTAL * CDIM) / 4);
}

// Round 9
// 251.307 us; speedup vs baseline: 1.3832x; 1.0326x over previous
//
#include <hip/hip_runtime.h>

#define R_TOTAL 12544
#define NTOK    784
#define CDIM    384
#define INNER   1152
#define NHEAD   8
#define HDIM    48
#define BATCH   16
#define SCALE   0.14433756729740643f   // 48^-0.5
#define LOG2E   1.4426950408889634f
#define SCLOG2E 0.20823509f            // SCALE * LOG2E (folded into K's BN affine)

typedef unsigned short u16;
typedef unsigned int   u32;
typedef __attribute__((ext_vector_type(8))) short short8;   // 8 bf16, 4 VGPRs
typedef __attribute__((ext_vector_type(4))) float floatx4;  // MFMA C/D

union V8 { uint4 u; short8 s; u16 h[8]; };

// workspace layout (BYTE offsets) — total 38.56 MB, byte-identical to rounds 2-8 (proven safe).
#define OB_OFF     28901376ull   // Yb bf16 [12544,1152] at 0; Ob bf16 [12544,384] here
#define ST_OFF     38535168ull   // fp32 stats: S1[2304] AB1[2304] S2[768] AB2[768]

__device__ __forceinline__ float b2f(u16 u) {
    union { float f; u32 i; } v; v.i = ((u32)u) << 16; return v.f;
}
__device__ __forceinline__ u16 f2b(float f) {
    union { float f; u32 i; } v; v.f = f;
    u32 r = v.i + 0x7FFFu + ((v.i >> 16) & 1u);   // RNE
    return (u16)(r >> 16);
}
// pack two fp32 -> two bf16 (RNE) in one v_perm_b32
__device__ __forceinline__ u32 pk2(float lo, float hi) {
    union { float f; u32 i; } a, b; a.f = lo; b.f = hi;
    u32 ra = a.i + 0x7FFFu + ((a.i >> 16) & 1u);
    u32 rb = b.i + 0x7FFFu + ((b.i >> 16) & 1u);
    return __builtin_amdgcn_perm(rb, ra, 0x07060302u);   // [rb.hi16 : ra.hi16]
}
__device__ __forceinline__ float hswish_f(float v) {
    return v * fminf(fmaxf(v + 3.f, 0.f), 6.f) * (1.f / 6.f);
}

__global__ __launch_bounds__(256) void zero_k(float* __restrict__ p, int n) {
    int i = blockIdx.x * 256 + threadIdx.x;
    if (i < n) p[i] = 0.f;
}

// ---------------------------------------------------------------- MFMA GEMM (+fused BN col stats)
template<int ABF16, int HSW, int OBF16>
__global__ __launch_bounds__(256) void gemm_mfma_k(
    const void* __restrict__ Ap, const float* __restrict__ Bfp,
    void* __restrict__ Cp, float* __restrict__ sums, int M, int Nout, int K)
{
    __shared__ u16 As[128 * 40];
    __shared__ u16 Bs[128 * 40];
    const int t = threadIdx.x;
    const int lane = t & 63, wv = t >> 6;
    const int l15 = lane & 15, quad = lane >> 4;
    const int wm = (wv & 1) * 64, wn = (wv >> 1) * 64;
    const int m0 = blockIdx.y * 128, n0 = blockIdx.x * 128;
    const floatx4 zf = {0.f, 0.f, 0.f, 0.f};

    floatx4 acc[4][4];
    #pragma unroll
    for (int i = 0; i < 4; i++)
        #pragma unroll
        for (int j = 0; j < 4; j++) acc[i][j] = zf;

    for (int k0 = 0; k0 < K; k0 += 32) {
        __syncthreads();
        #pragma unroll
        for (int it = 0; it < 2; it++) {
            const int flat = t + it * 256;
            const int rr = flat >> 2, ss = (flat & 3) * 8;
            uint4 aw;
            if (ABF16) {
                uint4 u = *(const uint4*)((const u16*)Ap + (size_t)(m0 + rr) * K + k0 + ss);
                if (HSW) {
                    aw.x = pk2(hswish_f(b2f((u16)(u.x & 0xffff))), hswish_f(b2f((u16)(u.x >> 16))));
                    aw.y = pk2(hswish_f(b2f((u16)(u.y & 0xffff))), hswish_f(b2f((u16)(u.y >> 16))));
                    aw.z = pk2(hswish_f(b2f((u16)(u.z & 0xffff))), hswish_f(b2f((u16)(u.z >> 16))));
                    aw.w = pk2(hswish_f(b2f((u16)(u.w & 0xffff))), hswish_f(b2f((u16)(u.w >> 16))));
                } else {
                    aw = u;
                }
            } else {
                const float* p = (const float*)Ap + (size_t)(m0 + rr) * K + k0 + ss;
                float4 f0 = *(const float4*)p, f1 = *(const float4*)(p + 4);
                aw.x = pk2(f0.x, f0.y); aw.y = pk2(f0.z, f0.w);
                aw.z = pk2(f1.x, f1.y); aw.w = pk2(f1.z, f1.w);
            }
            *(uint4*)&As[rr * 40 + ss] = aw;
            const float* q = Bfp + (size_t)(n0 + rr) * K + k0 + ss;
            float4 g0 = *(const float4*)q, g1 = *(const float4*)(q + 4);
            uint4 bw;
            bw.x = pk2(g0.x, g0.y); bw.y = pk2(g0.z, g0.w);
            bw.z = pk2(g1.x, g1.y); bw.w = pk2(g1.z, g1.w);
            *(uint4*)&Bs[rr * 40 + ss] = bw;
        }
        __syncthreads();
        short8 af[4], bfr[4];
        #pragma unroll
        for (int mi = 0; mi < 4; mi++)
            af[mi] = *(const short8*)&As[(wm + mi * 16 + l15) * 40 + quad * 8];
        #pragma unroll
        for (int ni = 0; ni < 4; ni++)
            bfr[ni] = *(const short8*)&Bs[(wn + ni * 16 + l15) * 40 + quad * 8];
        #pragma unroll
        for (int mi = 0; mi < 4; mi++)
            #pragma unroll
            for (int ni = 0; ni < 4; ni++)
                acc[mi][ni] = __builtin_amdgcn_mfma_f32_16x16x32_bf16(af[mi], bfr[ni], acc[mi][ni], 0, 0, 0);
    }

    float cs[4] = {0.f, 0.f, 0.f, 0.f}, cq[4] = {0.f, 0.f, 0.f, 0.f};
    #pragma unroll
    for (int mi = 0; mi < 4; mi++) {
        const int mbase = m0 + wm + mi * 16 + quad * 4;
        #pragma unroll
        for (int ni = 0; ni < 4; ni++) {
            const int n = n0 + wn + ni * 16 + l15;
            #pragma unroll
            for (int reg = 0; reg < 4; reg++) {
                size_t off = (size_t)(mbase + reg) * Nout + n;
                float v = acc[mi][ni][reg];
                float vv;
                if (OBF16) {
                    u16 hv = f2b(v);
                    ((u16*)Cp)[off] = hv;
                    vv = b2f(hv);
                } else {
                    ((float*)Cp)[off] = v;
                    vv = v;
                }
                cs[ni] += vv;
                cq[ni] += vv * vv;
            }
        }
    }
    #pragma unroll
    for (int ni = 0; ni < 4; ni++) {
        float s = cs[ni], sq = cq[ni];
        s  += __shfl_xor(s, 16);  s  += __shfl_xor(s, 32);
        sq += __shfl_xor(sq, 16); sq += __shfl_xor(sq, 32);
        if (quad == 0) {
            int col = n0 + wn + ni * 16 + l15;
            atomicAdd(&sums[col], s);
            atomicAdd(&sums[Nout + col], sq);
        }
    }
}

// sc0..sc1: column range whose affine (a, bb) is pre-multiplied by sfac
// (folds softmax SCALE*log2e into the K columns so attention uses raw v_exp_f32)
__global__ __launch_bounds__(256) void finalize_bn_k(
    const float* __restrict__ sums, const float* __restrict__ g,
    const float* __restrict__ bvec, float* __restrict__ ab, int Ncols, float invM,
    int sc0, int sc1, float sfac)
{
    int c = blockIdx.x * 256 + threadIdx.x;
    if (c >= Ncols) return;
    float mean = sums[c] * invM;
    float var  = sums[Ncols + c] * invM - mean * mean;
    float a    = g[c] * rsqrtf(var + 1e-5f);
    float f    = (c >= sc0 && c < sc1) ? sfac : 1.f;
    ab[c] = a * f;
    ab[Ncols + c] = (bvec[c] - mean * a) * f;
}

__global__ __launch_bounds__(256) void bn_apply_k(
    float* __restrict__ Z, const float* __restrict__ ab, int Ncols, int total4)
{
    for (int i4 = blockIdx.x * 256 + threadIdx.x; i4 < total4; i4 += gridDim.x * 256) {
        int col = (i4 * 4) % Ncols;
        float4 z  = *(float4*)(Z + (size_t)i4 * 4);
        float4 a4 = *(const float4*)(ab + col);
        float4 b4 = *(const float4*)(ab + Ncols + col);
        z.x = a4.x * z.x + b4.x; z.y = a4.y * z.y + b4.y;
        z.z = a4.z * z.z + b4.z; z.w = a4.w * z.w + b4.w;
        *(float4*)(Z + (size_t)i4 * 4) = z;
    }
}

__global__ __launch_bounds__(256) void bn_apply_bf16_k(
    u16* __restrict__ Z, const float* __restrict__ ab, int Ncols, int total8)
{
    int i8 = blockIdx.x * 256 + threadIdx.x;
    if (i8 >= total8) return;
    int col = (i8 * 8) % Ncols;
    uint4 u = *(uint4*)(Z + (size_t)i8 * 8);
    float4 A0 = *(const float4*)(ab + col),         A1 = *(const float4*)(ab + col + 4);
    float4 B0 = *(const float4*)(ab + Ncols + col), B1 = *(const float4*)(ab + Ncols + col + 4);
    uint4 o;
    o.x = pk2(fmaf(b2f((u16)(u.x & 0xffff)), A0.x, B0.x), fmaf(b2f((u16)(u.x >> 16)), A0.y, B0.y));
    o.y = pk2(fmaf(b2f((u16)(u.y & 0xffff)), A0.z, B0.z), fmaf(b2f((u16)(u.y >> 16)), A0.w, B0.w));
    o.z = pk2(fmaf(b2f((u16)(u.z & 0xffff)), A1.x, B1.x), fmaf(b2f((u16)(u.z >> 16)), A1.y, B1.y));
    o.w = pk2(fmaf(b2f((u16)(u.w & 0xffff)), A1.z, B1.z), fmaf(b2f((u16)(u.w >> 16)), A1.w, B1.w));
    *(uint4*)(Z + (size_t)i8 * 8) = o;
}

// 8x8 u16 transpose across 8 lanes (g = lane&7) via 3 butterfly stages.
__device__ __forceinline__ uint4 transpose8x8_u16(uint4 v, int g) {
    u32 r0 = v.x, r1 = v.y, r2 = v.z, r3 = v.w;
    {
        u32 t0 = (u32)__shfl_xor((int)r2, 4);
        u32 t1 = (u32)__shfl_xor((int)r3, 4);
        u32 t2 = (u32)__shfl_xor((int)r0, 4);
        u32 t3 = (u32)__shfl_xor((int)r1, 4);
        bool gb2 = (g >> 2) & 1;
        r0 = gb2 ? t0 : r0;
        r1 = gb2 ? t1 : r1;
        r2 = gb2 ? r2 : t2;
        r3 = gb2 ? r3 : t3;
    }
    {
        u32 t0 = (u32)__shfl_xor((int)r1, 2);
        u32 t1 = (u32)__shfl_xor((int)r0, 2);
        u32 t2 = (u32)__shfl_xor((int)r3, 2);
        u32 t3 = (u32)__shfl_xor((int)r2, 2);
        bool gb1 = (g >> 1) & 1;
        r0 = gb1 ? t0 : r0;
        r1 = gb1 ? r1 : t1;
        r2 = gb1 ? t2 : r2;
        r3 = gb1 ? r3 : t3;
    }
    {
        u32 t0 = (u32)__shfl_xor((int)r0, 1);
        u32 t1 = (u32)__shfl_xor((int)r1, 1);
        u32 t2 = (u32)__shfl_xor((int)r2, 1);
        u32 t3 = (u32)__shfl_xor((int)r3, 1);
        if (g & 1) {
            r0 = (r0 & 0xFFFF0000u) | (t0 >> 16);
            r1 = (r1 & 0xFFFF0000u) | (t1 >> 16);
            r2 = (r2 & 0xFFFF0000u) | (t2 >> 16);
            r3 = (r3 & 0xFFFF0000u) | (t3 >> 16);
        } else {
            r0 = (r0 & 0x0000FFFFu) | (t0 << 16);
            r1 = (r1 & 0x0000FFFFu) | (t1 << 16);
            r2 = (r2 & 0x0000FFFFu) | (t2 << 16);
            r3 = (r3 & 0x0000FFFFu) | (t3 << 16);
        }
    }
    return make_uint4(r0, r1, r2, r3);
}

// ---------------------------------------------------------------- MFMA flash attention v6
// 128-q blocks, swapped S^T=K*Q^T, K+V depth-1 reg prefetch, vt double-buffered,
// transpose-staged V (conflict-free). Softmax path: idx int4 gathers issued at top of
// iter (L2-latency hidden), raw v_exp_f32 (scales pre-folded into K's BN + bias row),
// key-mask only in the wave-uniform tail tile.
__global__ __launch_bounds__(256) void attn_mfma_k(
    const u16* __restrict__ Y,
    const float* __restrict__ biases, const int* __restrict__ idxs,
    u16* __restrict__ O)
{
    __shared__ u16 vt[2][6 * 64 * 8];       // double-buffered V^T, frag-order (12 KB)
    __shared__ u16 psm[4][2][2 * 64 * 8];   // per-wave, per-q-half P^T (16 KB)
    __shared__ float hb[NTOK];              // biases[h] * LOG2E

    const int t = threadIdx.x;
    const int lane = t & 63, wv = t >> 6;
    const int l15 = lane & 15, quad = lane >> 4;
    const int g8 = lane & 7, sg = lane >> 3;
    const int bh = blockIdx.x;
    const int b = bh >> 3, h = bh & 7;
    const int n0 = blockIdx.y * 128;
    const int bN = b * NTOK;
    const int colQ = h * HDIM, colK = CDIM + colQ, colV = 2 * CDIM + colQ;
    const floatx4 zf = {0.f, 0.f, 0.f, 0.f};

    if (t < 196) {
        float4 v = *(const float4*)(biases + (size_t)h * NTOK + (t << 2));
        v.x *= LOG2E; v.y *= LOG2E; v.z *= LOG2E; v.w *= LOG2E;
        *(float4*)&hb[t << 2] = v;
    }

    int qv[2], qr[2];
    #pragma unroll
    for (int qh = 0; qh < 2; qh++) {
        qv[qh] = n0 + qh * 64 + wv * 16 + l15;
        qr[qh] = qv[qh] < NTOK ? qv[qh] : NTOK - 1;
    }
    const int* idxrow[2] = { idxs + (size_t)qr[0] * NTOK, idxs + (size_t)qr[1] * NTOK };

    // Q B-frags: B[k=d][n=q=l15]; chunk1 zero for quad>=2 (d pad 48..63)
    short8 qf[2][2];
    #pragma unroll
    for (int qh = 0; qh < 2; qh++) {
        V8 a0, a1;
        a1.u = make_uint4(0u, 0u, 0u, 0u);
        const u16* src = Y + (size_t)(bN + qr[qh]) * INNER + colQ;
        a0.u = *(const uint4*)(src + quad * 8);
        if (quad < 2) a1.u = *(const uint4*)(src + 32 + quad * 8);
        qf[qh][0] = a0.s; qf[qh][1] = a1.s;
    }

    // V staging: wave wv stages d-seg wv (A) and 4+wv for wv<2 (B); 8x8 transpose in regs.
    const bool ownB = (wv < 2);
    const int dsA = wv, dsB = 4 + wv;
    const int dA = dsA * 8 + g8, dB = dsB * 8 + g8;
    const int vaddrA = (((dA >> 4) * 2 + (sg >> 2)) * 64 + (sg & 3) * 16 + (dA & 15)) * 8;
    const int vaddrB = (((dB >> 4) * 2 + (sg >> 2)) * 64 + (sg & 3) * 16 + (dB & 15)) * 8;

    V8 pvA, pvB;
    {   // preload V tile 0 and stage vt[0]
        const u16* src = Y + (size_t)(bN + lane) * INNER + colV;
        pvA.u = *(const uint4*)(src + dsA * 8);
        if (ownB) pvB.u = *(const uint4*)(src + dsB * 8);
        *(uint4*)&vt[0][vaddrA] = transpose8x8_u16(pvA.u, g8);
        if (ownB) *(uint4*)&vt[0][vaddrB] = transpose8x8_u16(pvB.u, g8);
    }

    // preload K A-frags for tile 0
    V8 kfr[4][2];
    #pragma unroll
    for (int sub = 0; sub < 4; sub++) {
        const u16* src = Y + (size_t)(bN + sub * 16 + l15) * INNER + colK;
        kfr[sub][0].u = *(const uint4*)(src + quad * 8);
        kfr[sub][1].u = *(const uint4*)(src + 32 + quad * 8);
    }

    float lsum[2] = {0.f, 0.f};
    floatx4 oacc[2][3];
    #pragma unroll
    for (int qh = 0; qh < 2; qh++)
        #pragma unroll
        for (int i = 0; i < 3; i++) oacc[qh][i] = zf;

    const int psbase = ((quad >> 1) * 16 + l15) * 8 + (quad & 1) * 4;

    for (int mt = 0; mt < 13; mt++) {
        const int m0k = mt * 64;
        const bool tail = (m0k == 768);
        __syncthreads();   // vt[mt&1] fully staged; hb/psm fenced at mt=0

        // ---- idx gathers for THIS tile (issued first; consumed after QK -> latency hidden)
        int4 ivc[2][4];
        #pragma unroll
        for (int qh = 0; qh < 2; qh++)
            #pragma unroll
            for (int sub = 0; sub < 4; sub++) {
                int kb = m0k + sub * 16 + quad * 4;
                kb = kb < NTOK - 4 ? kb : NTOK - 4;
                ivc[qh][sub] = *(const int4*)(idxrow[qh] + kb);
            }

        // ---- prefetch K(mt+1), V(mt+1) into regs
        V8 kn[4][2];
        const bool more = (mt + 1 < 13);
        if (more) {
            const int mn = m0k + 64;
            #pragma unroll
            for (int sub = 0; sub < 4; sub++) {
                int key = mn + sub * 16 + l15;
                int kr  = key < NTOK ? key : NTOK - 1;
                const u16* src = Y + (size_t)(bN + kr) * INNER + colK;
                kn[sub][0].u = *(const uint4*)(src + quad * 8);
                kn[sub][1].u = *(const uint4*)(src + 32 + quad * 8);
            }
            int kv = mn + lane; kv = kv < NTOK ? kv : NTOK - 1;
            const u16* src = Y + (size_t)(bN + kv) * INNER + colV;
            pvA.u = *(const uint4*)(src + dsA * 8);
            if (ownB) pvB.u = *(const uint4*)(src + dsB * 8);
        }

        // ---- per q-half: S^T = K*Q^T, then p = 2^(s + bias)  (scales pre-folded)
        #pragma unroll
        for (int qh = 0; qh < 2; qh++) {
            floatx4 sf[4];
            #pragma unroll
            for (int sub = 0; sub < 4; sub++) {
                floatx4 c = zf;
                c = __builtin_amdgcn_mfma_f32_16x16x32_bf16(kfr[sub][0].s, qf[qh][0], c, 0, 0, 0);
                c = __builtin_amdgcn_mfma_f32_16x16x32_bf16(kfr[sub][1].s, qf[qh][1], c, 0, 0, 0);
                sf[sub] = c;
            }
            #pragma unroll
            for (int sub = 0; sub < 4; sub++) {
                const int4 iv = ivc[qh][sub];
                float a0 = sf[sub][0] + hb[iv.x];
                float a1 = sf[sub][1] + hb[iv.y];
                float a2 = sf[sub][2] + hb[iv.z];
                float a3 = sf[sub][3] + hb[iv.w];
                float pr[4];
                asm("v_exp_f32 %0, %1" : "=v"(pr[0]) : "v"(a0));
                asm("v_exp_f32 %0, %1" : "=v"(pr[1]) : "v"(a1));
                asm("v_exp_f32 %0, %1" : "=v"(pr[2]) : "v"(a2));
                asm("v_exp_f32 %0, %1" : "=v"(pr[3]) : "v"(a3));
                if (tail) {   // wave-uniform: only tile 12 has keys >= 784
                    const int kb0 = m0k + sub * 16 + quad * 4;
                    #pragma unroll
                    for (int reg = 0; reg < 4; reg++)
                        if (kb0 + reg >= NTOK) pr[reg] = 0.f;
                }
                lsum[qh] += (pr[0] + pr[1]) + (pr[2] + pr[3]);
                int addr = psbase + (sub >> 1) * 512 + (sub & 1) * 256;
                *(uint2*)&psm[wv][qh][addr] = make_uint2(pk2(pr[0], pr[1]), pk2(pr[2], pr[3]));
            }
        }

        // ---- stage vt for next tile (transpose prefetched regs, b128 conflict-free)
        if (more) {
            u16* vtb = vt[(mt + 1) & 1];
            *(uint4*)&vtb[vaddrA] = transpose8x8_u16(pvA.u, g8);
            if (ownB) *(uint4*)&vtb[vaddrB] = transpose8x8_u16(pvB.u, g8);
        }

        // ---- O^T += V^T * P^T (V frags shared across q-halves)
        const u16* vtb = vt[mt & 1];
        #pragma unroll
        for (int kc = 0; kc < 2; kc++) {
            short8 pb0 = *(const short8*)&psm[wv][0][(kc * 64 + lane) * 8];
            short8 pb1 = *(const short8*)&psm[wv][1][(kc * 64 + lane) * 8];
            #pragma unroll
            for (int ns = 0; ns < 3; ns++) {
                short8 va = *(const short8*)&vtb[((ns * 2 + kc) * 64 + lane) * 8];
                oacc[0][ns] = __builtin_amdgcn_mfma_f32_16x16x32_bf16(va, pb0, oacc[0][ns], 0, 0, 0);
                oacc[1][ns] = __builtin_amdgcn_mfma_f32_16x16x32_bf16(va, pb1, oacc[1][ns], 0, 0, 0);
            }
        }

        // ---- rotate K pipeline
        if (more) {
            #pragma unroll
            for (int sub = 0; sub < 4; sub++) {
                kfr[sub][0] = kn[sub][0];
                kfr[sub][1] = kn[sub][1];
            }
        }
    }

    // ---- epilogue
    #pragma unroll
    for (int qh = 0; qh < 2; qh++) {
        float ls = lsum[qh];
        ls += __shfl_xor(ls, 16);
        ls += __shfl_xor(ls, 32);
        if (qv[qh] < NTOK) {
            float rl = 1.f / ls;
            u16* dst = O + (size_t)(bN + qv[qh]) * CDIM + colQ;
            #pragma unroll
            for (int ns = 0; ns < 3; ns++)
                #pragma unroll
                for (int reg = 0; reg < 4; reg++)
                    dst[ns * 16 + quad * 4 + reg] = f2b(hswish_f(oacc[qh][ns][reg] * rl));
        }
    }
}

// ---------------------------------------------------------------- launch
extern "C" void kernel_launch(void* const* d_in, const int* in_sizes, int n_in,
                              void* d_out, int out_size, void* d_ws, size_t ws_size,
                              hipStream_t stream)
{
    const float* x     = (const float*)d_in[0];
    const float* Wqkv  = (const float*)d_in[1];
    const float* g1    = (const float*)d_in[2];
    const float* b1    = (const float*)d_in[3];
    const float* Wproj = (const float*)d_in[4];
    const float* g2    = (const float*)d_in[5];
    const float* b2    = (const float*)d_in[6];
    const float* bias  = (const float*)d_in[7];
    const int*   idxs  = (const int*)d_in[8];
    float* out = (float*)d_out;
    char*  wsb = (char*)d_ws;

    u16*   Yb  = (u16*)wsb;
    u16*   Ob  = (u16*)(wsb + OB_OFF);
    float* S1  = (float*)(wsb + ST_OFF);
    float* AB1 = S1 + 2304;
    float* S2  = AB1 + 2304;
    float* AB2 = S2 + 768;

    zero_k<<<24, 256, 0, stream>>>(S1, 6144);

    // GEMM1 (+fused BN1 stats): Ybf16 = x @ Wqkv^T
    gemm_mfma_k<0, 0, 1><<<dim3(INNER / 128, R_TOTAL / 128), 256, 0, stream>>>(
        x, Wqkv, Yb, S1, R_TOTAL, INNER, CDIM);

    // finalize BN1 (K columns pre-scaled by SCALE*log2e for the exp2 softmax path)
    finalize_bn_k<<<(INNER + 255) / 256, 256, 0, stream>>>(
        S1, g1, b1, AB1, INNER, 1.f / R_TOTAL, CDIM, 2 * CDIM, SCLOG2E);
    bn_apply_bf16_k<<<(R_TOTAL * INNER / 8 + 255) / 256, 256, 0, stream>>>(
        Yb, AB1, INNER, R_TOTAL * INNER / 8);

    // attention
    attn_mfma_k<<<dim3(NHEAD * BATCH, 7), 256, 0, stream>>>(Yb, bias, idxs, Ob);

    // GEMM2 (+fused BN2 stats): out = O_hsw @ Wproj^T
    gemm_mfma_k<1, 0, 0><<<dim3(CDIM / 128, R_TOTAL / 128), 256, 0, stream>>>(
        Ob, Wproj, out, S2, R_TOTAL, CDIM, CDIM);

    finalize_bn_k<<<(CDIM + 255) / 256, 256, 0, stream>>>(
        S2, g2, b2, AB2, CDIM, 1.f / R_TOTAL, 0, 0, 1.f);
    bn_apply_k<<<1024, 256, 0, stream>>>(out, AB2, CDIM, (R_TOTAL * CDIM) / 4);
}

// Round 10
// 242.178 us; speedup vs baseline: 1.4354x; 1.0377x over previous
//
#include <hip/hip_runtime.h>

#define R_TOTAL 12544
#define NTOK    784
#define CDIM    384
#define INNER   1152
#define NHEAD   8
#define HDIM    48
#define BATCH   16
#define HSEG    37632                  // 784*48 elements per (b,h,part) panel
#define SCALE   0.14433756729740643f   // 48^-0.5
#define LOG2E   1.4426950408889634f
#define SCLOG2E 0.20823509f            // SCALE * LOG2E (folded into K's BN affine)

typedef unsigned short u16;
typedef unsigned int   u32;
typedef __attribute__((ext_vector_type(8))) short short8;   // 8 bf16, 4 VGPRs
typedef __attribute__((ext_vector_type(4))) float floatx4;  // MFMA C/D

union V8 { uint4 u; short8 s; u16 h[8]; };

// workspace layout (BYTE offsets) — total 38.56 MB, byte-identical to rounds 2-9 (proven safe).
// Yb is now HEAD-MAJOR: [b][h][{q,k,v}][784][48] bf16 (same total size).
#define OB_OFF     28901376ull   // Ob bf16 [12544,384]
#define ST_OFF     38535168ull   // fp32 stats: S1[2304] AB1[2304] S2[768] AB2[768]

__device__ __forceinline__ float b2f(u16 u) {
    union { float f; u32 i; } v; v.i = ((u32)u) << 16; return v.f;
}
__device__ __forceinline__ u16 f2b(float f) {
    union { float f; u32 i; } v; v.f = f;
    u32 r = v.i + 0x7FFFu + ((v.i >> 16) & 1u);   // RNE
    return (u16)(r >> 16);
}
// pack two fp32 -> two bf16 (RNE) in one v_perm_b32
__device__ __forceinline__ u32 pk2(float lo, float hi) {
    union { float f; u32 i; } a, b; a.f = lo; b.f = hi;
    u32 ra = a.i + 0x7FFFu + ((a.i >> 16) & 1u);
    u32 rb = b.i + 0x7FFFu + ((b.i >> 16) & 1u);
    return __builtin_amdgcn_perm(rb, ra, 0x07060302u);   // [rb.hi16 : ra.hi16]
}
__device__ __forceinline__ float hswish_f(float v) {
    return v * fminf(fmaxf(v + 3.f, 0.f), 6.f) * (1.f / 6.f);
}

__global__ __launch_bounds__(256) void zero_k(float* __restrict__ p, int n) {
    int i = blockIdx.x * 256 + threadIdx.x;
    if (i < n) p[i] = 0.f;
}

// ---------------------------------------------------------------- MFMA GEMM (+fused BN col stats)
// HEADM: store bf16 output in head-major [b][h][part][n][d] layout (GEMM1 -> attention).
template<int ABF16, int HSW, int OBF16, int HEADM>
__global__ __launch_bounds__(256) void gemm_mfma_k(
    const void* __restrict__ Ap, const float* __restrict__ Bfp,
    void* __restrict__ Cp, float* __restrict__ sums, int M, int Nout, int K)
{
    __shared__ u16 As[128 * 40];
    __shared__ u16 Bs[128 * 40];
    const int t = threadIdx.x;
    const int lane = t & 63, wv = t >> 6;
    const int l15 = lane & 15, quad = lane >> 4;
    const int wm = (wv & 1) * 64, wn = (wv >> 1) * 64;
    const int m0 = blockIdx.y * 128, n0 = blockIdx.x * 128;
    const floatx4 zf = {0.f, 0.f, 0.f, 0.f};

    floatx4 acc[4][4];
    #pragma unroll
    for (int i = 0; i < 4; i++)
        #pragma unroll
        for (int j = 0; j < 4; j++) acc[i][j] = zf;

    for (int k0 = 0; k0 < K; k0 += 32) {
        __syncthreads();
        #pragma unroll
        for (int it = 0; it < 2; it++) {
            const int flat = t + it * 256;
            const int rr = flat >> 2, ss = (flat & 3) * 8;
            uint4 aw;
            if (ABF16) {
                uint4 u = *(const uint4*)((const u16*)Ap + (size_t)(m0 + rr) * K + k0 + ss);
                if (HSW) {
                    aw.x = pk2(hswish_f(b2f((u16)(u.x & 0xffff))), hswish_f(b2f((u16)(u.x >> 16))));
                    aw.y = pk2(hswish_f(b2f((u16)(u.y & 0xffff))), hswish_f(b2f((u16)(u.y >> 16))));
                    aw.z = pk2(hswish_f(b2f((u16)(u.z & 0xffff))), hswish_f(b2f((u16)(u.z >> 16))));
                    aw.w = pk2(hswish_f(b2f((u16)(u.w & 0xffff))), hswish_f(b2f((u16)(u.w >> 16))));
                } else {
                    aw = u;
                }
            } else {
                const float* p = (const float*)Ap + (size_t)(m0 + rr) * K + k0 + ss;
                float4 f0 = *(const float4*)p, f1 = *(const float4*)(p + 4);
                aw.x = pk2(f0.x, f0.y); aw.y = pk2(f0.z, f0.w);
                aw.z = pk2(f1.x, f1.y); aw.w = pk2(f1.z, f1.w);
            }
            *(uint4*)&As[rr * 40 + ss] = aw;
            const float* q = Bfp + (size_t)(n0 + rr) * K + k0 + ss;
            float4 g0 = *(const float4*)q, g1 = *(const float4*)(q + 4);
            uint4 bw;
            bw.x = pk2(g0.x, g0.y); bw.y = pk2(g0.z, g0.w);
            bw.z = pk2(g1.x, g1.y); bw.w = pk2(g1.z, g1.w);
            *(uint4*)&Bs[rr * 40 + ss] = bw;
        }
        __syncthreads();
        short8 af[4], bfr[4];
        #pragma unroll
        for (int mi = 0; mi < 4; mi++)
            af[mi] = *(const short8*)&As[(wm + mi * 16 + l15) * 40 + quad * 8];
        #pragma unroll
        for (int ni = 0; ni < 4; ni++)
            bfr[ni] = *(const short8*)&Bs[(wn + ni * 16 + l15) * 40 + quad * 8];
        #pragma unroll
        for (int mi = 0; mi < 4; mi++)
            #pragma unroll
            for (int ni = 0; ni < 4; ni++)
                acc[mi][ni] = __builtin_amdgcn_mfma_f32_16x16x32_bf16(af[mi], bfr[ni], acc[mi][ni], 0, 0, 0);
    }

    float cs[4] = {0.f, 0.f, 0.f, 0.f}, cq[4] = {0.f, 0.f, 0.f, 0.f};
    #pragma unroll
    for (int mi = 0; mi < 4; mi++) {
        const int mbase = m0 + wm + mi * 16 + quad * 4;
        int bb_[4], nn_[4];
        if (HEADM) {
            #pragma unroll
            for (int reg = 0; reg < 4; reg++) {
                int m = mbase + reg;
                int bv = ((m >> 4) * 1338) >> 16;   // m/784 for m<12544 (=16*49; x/49=(x*1338)>>16)
                bb_[reg] = bv;
                nn_[reg] = m - bv * 784;
            }
        }
        #pragma unroll
        for (int ni = 0; ni < 4; ni++) {
            const int c0 = n0 + wn + ni * 16;      // wave-uniform; 16-col group never straddles h
            const int n = c0 + l15;
            int part = 0, hcol = 0, d0 = 0;
            if (HEADM) {
                part = c0 / 384;
                int rem = c0 - part * 384;
                hcol = rem / 48;
                d0 = rem - hcol * 48;
            }
            #pragma unroll
            for (int reg = 0; reg < 4; reg++) {
                float v = acc[mi][ni][reg];
                float vv;
                if (OBF16) {
                    u16 hv = f2b(v);
                    size_t off;
                    if (HEADM)
                        off = (size_t)((bb_[reg] * 8 + hcol) * 3 + part) * HSEG
                            + (size_t)nn_[reg] * 48 + d0 + l15;
                    else
                        off = (size_t)(mbase + reg) * Nout + n;
                    ((u16*)Cp)[off] = hv;
                    vv = b2f(hv);
                } else {
                    ((float*)Cp)[(size_t)(mbase + reg) * Nout + n] = v;
                    vv = v;
                }
                cs[ni] += vv;
                cq[ni] += vv * vv;
            }
        }
    }
    #pragma unroll
    for (int ni = 0; ni < 4; ni++) {
        float s = cs[ni], sq = cq[ni];
        s  += __shfl_xor(s, 16);  s  += __shfl_xor(s, 32);
        sq += __shfl_xor(sq, 16); sq += __shfl_xor(sq, 32);
        if (quad == 0) {
            int col = n0 + wn + ni * 16 + l15;
            atomicAdd(&sums[col], s);
            atomicAdd(&sums[Nout + col], sq);
        }
    }
}

// sc0..sc1: logical-column range whose affine is pre-scaled by sfac (K cols: SCALE*log2e)
__global__ __launch_bounds__(256) void finalize_bn_k(
    const float* __restrict__ sums, const float* __restrict__ g,
    const float* __restrict__ bvec, float* __restrict__ ab, int Ncols, float invM,
    int sc0, int sc1, float sfac)
{
    int c = blockIdx.x * 256 + threadIdx.x;
    if (c >= Ncols) return;
    float mean = sums[c] * invM;
    float var  = sums[Ncols + c] * invM - mean * mean;
    float a    = g[c] * rsqrtf(var + 1e-5f);
    float f    = (c >= sc0 && c < sc1) ? sfac : 1.f;
    ab[c] = a * f;
    ab[Ncols + c] = (bvec[c] - mean * a) * f;
}

__global__ __launch_bounds__(256) void bn_apply_k(
    float* __restrict__ Z, const float* __restrict__ ab, int Ncols, int total4)
{
    for (int i4 = blockIdx.x * 256 + threadIdx.x; i4 < total4; i4 += gridDim.x * 256) {
        int col = (i4 * 4) % Ncols;
        float4 z  = *(float4*)(Z + (size_t)i4 * 4);
        float4 a4 = *(const float4*)(ab + col);
        float4 b4 = *(const float4*)(ab + Ncols + col);
        z.x = a4.x * z.x + b4.x; z.y = a4.y * z.y + b4.y;
        z.z = a4.z * z.z + b4.z; z.w = a4.w * z.w + b4.w;
        *(float4*)(Z + (size_t)i4 * 4) = z;
    }
}

// bf16 in-place BN apply over HEAD-MAJOR Y: logical col derived from physical index
__global__ __launch_bounds__(256) void bn_apply_bf16_k(
    u16* __restrict__ Z, const float* __restrict__ ab, int total8)
{
    int i8 = blockIdx.x * 256 + threadIdx.x;
    if (i8 >= total8) return;
    int e0  = i8 * 8;
    int seg = e0 / HSEG;                 // (b*8+h)*3 + part
    int rem = e0 - seg * HSEG;           // n*48 + d (d multiple of 8)
    int d0  = rem % 48;
    int part = seg % 3;
    int hh   = (seg / 3) & 7;
    int col  = part * 384 + hh * 48 + d0;
    uint4 u = *(uint4*)(Z + (size_t)i8 * 8);
    float4 A0 = *(const float4*)(ab + col),        A1 = *(const float4*)(ab + col + 4);
    float4 B0 = *(const float4*)(ab + 1152 + col), B1 = *(const float4*)(ab + 1152 + col + 4);
    uint4 o;
    o.x = pk2(fmaf(b2f((u16)(u.x & 0xffff)), A0.x, B0.x), fmaf(b2f((u16)(u.x >> 16)), A0.y, B0.y));
    o.y = pk2(fmaf(b2f((u16)(u.y & 0xffff)), A0.z, B0.z), fmaf(b2f((u16)(u.y >> 16)), A0.w, B0.w));
    o.z = pk2(fmaf(b2f((u16)(u.z & 0xffff)), A1.x, B1.x), fmaf(b2f((u16)(u.z >> 16)), A1.y, B1.y));
    o.w = pk2(fmaf(b2f((u16)(u.w & 0xffff)), A1.z, B1.z), fmaf(b2f((u16)(u.w >> 16)), A1.w, B1.w));
    *(uint4*)(Z + (size_t)i8 * 8) = o;
}

// 8x8 u16 transpose across 8 lanes (g = lane&7) via 3 butterfly stages.
__device__ __forceinline__ uint4 transpose8x8_u16(uint4 v, int g) {
    u32 r0 = v.x, r1 = v.y, r2 = v.z, r3 = v.w;
    {
        u32 t0 = (u32)__shfl_xor((int)r2, 4);
        u32 t1 = (u32)__shfl_xor((int)r3, 4);
        u32 t2 = (u32)__shfl_xor((int)r0, 4);
        u32 t3 = (u32)__shfl_xor((int)r1, 4);
        bool gb2 = (g >> 2) & 1;
        r0 = gb2 ? t0 : r0;
        r1 = gb2 ? t1 : r1;
        r2 = gb2 ? r2 : t2;
        r3 = gb2 ? r3 : t3;
    }
    {
        u32 t0 = (u32)__shfl_xor((int)r1, 2);
        u32 t1 = (u32)__shfl_xor((int)r0, 2);
        u32 t2 = (u32)__shfl_xor((int)r3, 2);
        u32 t3 = (u32)__shfl_xor((int)r2, 2);
        bool gb1 = (g >> 1) & 1;
        r0 = gb1 ? t0 : r0;
        r1 = gb1 ? r1 : t1;
        r2 = gb1 ? t2 : r2;
        r3 = gb1 ? r3 : t3;
    }
    {
        u32 t0 = (u32)__shfl_xor((int)r0, 1);
        u32 t1 = (u32)__shfl_xor((int)r1, 1);
        u32 t2 = (u32)__shfl_xor((int)r2, 1);
        u32 t3 = (u32)__shfl_xor((int)r3, 1);
        if (g & 1) {
            r0 = (r0 & 0xFFFF0000u) | (t0 >> 16);
            r1 = (r1 & 0xFFFF0000u) | (t1 >> 16);
            r2 = (r2 & 0xFFFF0000u) | (t2 >> 16);
            r3 = (r3 & 0xFFFF0000u) | (t3 >> 16);
        } else {
            r0 = (r0 & 0x0000FFFFu) | (t0 << 16);
            r1 = (r1 & 0x0000FFFFu) | (t1 << 16);
            r2 = (r2 & 0x0000FFFFu) | (t2 << 16);
            r3 = (r3 & 0x0000FFFFu) | (t3 << 16);
        }
    }
    return make_uint4(r0, r1, r2, r3);
}

// ---------------------------------------------------------------- MFMA flash attention v7
// HEAD-MAJOR Y: per-(b,h) contiguous 75KB Q/K/V panels -> sequential streams, no line overfetch.
__global__ __launch_bounds__(256) void attn_mfma_k(
    const u16* __restrict__ Y,
    const float* __restrict__ biases, const int* __restrict__ idxs,
    u16* __restrict__ O)
{
    __shared__ u16 vt[2][6 * 64 * 8];       // double-buffered V^T, frag-order (12 KB)
    __shared__ u16 psm[4][2][2 * 64 * 8];   // per-wave, per-q-half P^T (16 KB)
    __shared__ float hb[NTOK];              // biases[h] * LOG2E

    const int t = threadIdx.x;
    const int lane = t & 63, wv = t >> 6;
    const int l15 = lane & 15, quad = lane >> 4;
    const int g8 = lane & 7, sg = lane >> 3;
    const int bh = blockIdx.x;
    const int b = bh >> 3, h = bh & 7;
    const int n0 = blockIdx.y * 128;
    const int bN = b * NTOK;
    const floatx4 zf = {0.f, 0.f, 0.f, 0.f};

    const u16* Qb = Y + (size_t)(bh * 3) * HSEG;
    const u16* Kb = Qb + HSEG;
    const u16* Vb = Qb + 2 * HSEG;

    if (t < 196) {
        float4 v = *(const float4*)(biases + (size_t)h * NTOK + (t << 2));
        v.x *= LOG2E; v.y *= LOG2E; v.z *= LOG2E; v.w *= LOG2E;
        *(float4*)&hb[t << 2] = v;
    }

    int qv[2], qr[2];
    #pragma unroll
    for (int qh = 0; qh < 2; qh++) {
        qv[qh] = n0 + qh * 64 + wv * 16 + l15;
        qr[qh] = qv[qh] < NTOK ? qv[qh] : NTOK - 1;
    }
    const int* idxrow[2] = { idxs + (size_t)qr[0] * NTOK, idxs + (size_t)qr[1] * NTOK };

    // Q B-frags: B[k=d][n=q=l15]; chunk1 zero for quad>=2 (d pad 48..63)
    short8 qf[2][2];
    #pragma unroll
    for (int qh = 0; qh < 2; qh++) {
        V8 a0, a1;
        a1.u = make_uint4(0u, 0u, 0u, 0u);
        const u16* src = Qb + (size_t)qr[qh] * 48;
        a0.u = *(const uint4*)(src + quad * 8);
        if (quad < 2) a1.u = *(const uint4*)(src + 32 + quad * 8);
        qf[qh][0] = a0.s; qf[qh][1] = a1.s;
    }

    // V staging: wave wv stages d-seg wv (A) and 4+wv for wv<2 (B); 8x8 transpose in regs.
    const bool ownB = (wv < 2);
    const int dsA = wv, dsB = 4 + wv;
    const int dA = dsA * 8 + g8, dB = dsB * 8 + g8;
    const int vaddrA = (((dA >> 4) * 2 + (sg >> 2)) * 64 + (sg & 3) * 16 + (dA & 15)) * 8;
    const int vaddrB = (((dB >> 4) * 2 + (sg >> 2)) * 64 + (sg & 3) * 16 + (dB & 15)) * 8;

    V8 pvA, pvB;
    {   // preload V tile 0 and stage vt[0]
        const u16* src = Vb + (size_t)lane * 48;
        pvA.u = *(const uint4*)(src + dsA * 8);
        if (ownB) pvB.u = *(const uint4*)(src + dsB * 8);
        *(uint4*)&vt[0][vaddrA] = transpose8x8_u16(pvA.u, g8);
        if (ownB) *(uint4*)&vt[0][vaddrB] = transpose8x8_u16(pvB.u, g8);
    }

    // preload K A-frags for tile 0
    V8 kfr[4][2];
    #pragma unroll
    for (int sub = 0; sub < 4; sub++) {
        const u16* src = Kb + (size_t)(sub * 16 + l15) * 48;
        kfr[sub][0].u = *(const uint4*)(src + quad * 8);
        kfr[sub][1].u = *(const uint4*)(src + 32 + quad * 8);  // quad>=2: next-row bf16, x0 on B side
    }

    float lsum[2] = {0.f, 0.f};
    floatx4 oacc[2][3];
    #pragma unroll
    for (int qh = 0; qh < 2; qh++)
        #pragma unroll
        for (int i = 0; i < 3; i++) oacc[qh][i] = zf;

    const int psbase = ((quad >> 1) * 16 + l15) * 8 + (quad & 1) * 4;

    for (int mt = 0; mt < 13; mt++) {
        const int m0k = mt * 64;
        const bool tail = (m0k == 768);
        __syncthreads();   // vt[mt&1] fully staged; hb/psm fenced at mt=0

        // ---- idx gathers for THIS tile (issued first; consumed after QK)
        int4 ivc[2][4];
        #pragma unroll
        for (int qh = 0; qh < 2; qh++)
            #pragma unroll
            for (int sub = 0; sub < 4; sub++) {
                int kb = m0k + sub * 16 + quad * 4;
                kb = kb < NTOK - 4 ? kb : NTOK - 4;
                ivc[qh][sub] = *(const int4*)(idxrow[qh] + kb);
            }

        // ---- prefetch K(mt+1), V(mt+1) into regs
        V8 kn[4][2];
        const bool more = (mt + 1 < 13);
        if (more) {
            const int mn = m0k + 64;
            #pragma unroll
            for (int sub = 0; sub < 4; sub++) {
                int key = mn + sub * 16 + l15;
                int kr  = key < NTOK ? key : NTOK - 1;
                const u16* src = Kb + (size_t)kr * 48;
                kn[sub][0].u = *(const uint4*)(src + quad * 8);
                kn[sub][1].u = *(const uint4*)(src + 32 + quad * 8);
            }
            int kv = mn + lane; kv = kv < NTOK ? kv : NTOK - 1;
            const u16* src = Vb + (size_t)kv * 48;
            pvA.u = *(const uint4*)(src + dsA * 8);
            if (ownB) pvB.u = *(const uint4*)(src + dsB * 8);
        }

        // ---- per q-half: S^T = K*Q^T, then p = 2^(s + bias)
        #pragma unroll
        for (int qh = 0; qh < 2; qh++) {
            floatx4 sf[4];
            #pragma unroll
            for (int sub = 0; sub < 4; sub++) {
                floatx4 c = zf;
                c = __builtin_amdgcn_mfma_f32_16x16x32_bf16(kfr[sub][0].s, qf[qh][0], c, 0, 0, 0);
                c = __builtin_amdgcn_mfma_f32_16x16x32_bf16(kfr[sub][1].s, qf[qh][1], c, 0, 0, 0);
                sf[sub] = c;
            }
            #pragma unroll
            for (int sub = 0; sub < 4; sub++) {
                const int4 iv = ivc[qh][sub];
                float a0 = sf[sub][0] + hb[iv.x];
                float a1 = sf[sub][1] + hb[iv.y];
                float a2 = sf[sub][2] + hb[iv.z];
                float a3 = sf[sub][3] + hb[iv.w];
                float pr[4];
                asm("v_exp_f32 %0, %1" : "=v"(pr[0]) : "v"(a0));
                asm("v_exp_f32 %0, %1" : "=v"(pr[1]) : "v"(a1));
                asm("v_exp_f32 %0, %1" : "=v"(pr[2]) : "v"(a2));
                asm("v_exp_f32 %0, %1" : "=v"(pr[3]) : "v"(a3));
                if (tail) {   // wave-uniform: only tile 12 has keys >= 784
                    const int kb0 = m0k + sub * 16 + quad * 4;
                    #pragma unroll
                    for (int reg = 0; reg < 4; reg++)
                        if (kb0 + reg >= NTOK) pr[reg] = 0.f;
                }
                lsum[qh] += (pr[0] + pr[1]) + (pr[2] + pr[3]);
                int addr = psbase + (sub >> 1) * 512 + (sub & 1) * 256;
                *(uint2*)&psm[wv][qh][addr] = make_uint2(pk2(pr[0], pr[1]), pk2(pr[2], pr[3]));
            }
        }

        // ---- stage vt for next tile
        if (more) {
            u16* vtb = vt[(mt + 1) & 1];
            *(uint4*)&vtb[vaddrA] = transpose8x8_u16(pvA.u, g8);
            if (ownB) *(uint4*)&vtb[vaddrB] = transpose8x8_u16(pvB.u, g8);
        }

        // ---- O^T += V^T * P^T (V frags shared across q-halves)
        const u16* vtb = vt[mt & 1];
        #pragma unroll
        for (int kc = 0; kc < 2; kc++) {
            short8 pb0 = *(const short8*)&psm[wv][0][(kc * 64 + lane) * 8];
            short8 pb1 = *(const short8*)&psm[wv][1][(kc * 64 + lane) * 8];
            #pragma unroll
            for (int ns = 0; ns < 3; ns++) {
                short8 va = *(const short8*)&vtb[((ns * 2 + kc) * 64 + lane) * 8];
                oacc[0][ns] = __builtin_amdgcn_mfma_f32_16x16x32_bf16(va, pb0, oacc[0][ns], 0, 0, 0);
                oacc[1][ns] = __builtin_amdgcn_mfma_f32_16x16x32_bf16(va, pb1, oacc[1][ns], 0, 0, 0);
            }
        }

        // ---- rotate K pipeline
        if (more) {
            #pragma unroll
            for (int sub = 0; sub < 4; sub++) {
                kfr[sub][0] = kn[sub][0];
                kfr[sub][1] = kn[sub][1];
            }
        }
    }

    // ---- epilogue (Ob stays row-major [12544,384] for GEMM2)
    #pragma unroll
    for (int qh = 0; qh < 2; qh++) {
        float ls = lsum[qh];
        ls += __shfl_xor(ls, 16);
        ls += __shfl_xor(ls, 32);
        if (qv[qh] < NTOK) {
            float rl = 1.f / ls;
            u16* dst = O + (size_t)(bN + qv[qh]) * CDIM + h * HDIM;
            #pragma unroll
            for (int ns = 0; ns < 3; ns++)
                #pragma unroll
                for (int reg = 0; reg < 4; reg++)
                    dst[ns * 16 + quad * 4 + reg] = f2b(hswish_f(oacc[qh][ns][reg] * rl));
        }
    }
}

// ---------------------------------------------------------------- launch
extern "C" void kernel_launch(void* const* d_in, const int* in_sizes, int n_in,
                              void* d_out, int out_size, void* d_ws, size_t ws_size,
                              hipStream_t stream)
{
    const float* x     = (const float*)d_in[0];
    const float* Wqkv  = (const float*)d_in[1];
    const float* g1    = (const float*)d_in[2];
    const float* b1    = (const float*)d_in[3];
    const float* Wproj = (const float*)d_in[4];
    const float* g2    = (const float*)d_in[5];
    const float* b2    = (const float*)d_in[6];
    const float* bias  = (const float*)d_in[7];
    const int*   idxs  = (const int*)d_in[8];
    float* out = (float*)d_out;
    char*  wsb = (char*)d_ws;

    u16*   Yb  = (u16*)wsb;
    u16*   Ob  = (u16*)(wsb + OB_OFF);
    float* S1  = (float*)(wsb + ST_OFF);
    float* AB1 = S1 + 2304;
    float* S2  = AB1 + 2304;
    float* AB2 = S2 + 768;

    zero_k<<<24, 256, 0, stream>>>(S1, 6144);

    // GEMM1 (+fused BN1 stats), head-major output
    gemm_mfma_k<0, 0, 1, 1><<<dim3(INNER / 128, R_TOTAL / 128), 256, 0, stream>>>(
        x, Wqkv, Yb, S1, R_TOTAL, INNER, CDIM);

    finalize_bn_k<<<(INNER + 255) / 256, 256, 0, stream>>>(
        S1, g1, b1, AB1, INNER, 1.f / R_TOTAL, CDIM, 2 * CDIM, SCLOG2E);
    bn_apply_bf16_k<<<(R_TOTAL * INNER / 8 + 255) / 256, 256, 0, stream>>>(
        Yb, AB1, R_TOTAL * INNER / 8);

    // attention over head-major panels
    attn_mfma_k<<<dim3(NHEAD * BATCH, 7), 256, 0, stream>>>(Yb, bias, idxs, Ob);

    // GEMM2 (+fused BN2 stats): out = O_hsw @ Wproj^T
    gemm_mfma_k<1, 0, 0, 0><<<dim3(CDIM / 128, R_TOTAL / 128), 256, 0, stream>>>(
        Ob, Wproj, out, S2, R_TOTAL, CDIM, CDIM);

    finalize_bn_k<<<(CDIM + 255) / 256, 256, 0, stream>>>(
        S2, g2, b2, AB2, CDIM, 1.f / R_TOTAL, 0, 0, 1.f);
    bn_apply_k<<<1024, 256, 0, stream>>>(out, AB2, CDIM, (R_TOTAL * CDIM) / 4);
}